// Round 1
// 597.647 us; speedup vs baseline: 1.0403x; 1.0403x over previous
//
#include <hip/hip_runtime.h>
#include <hip/hip_bf16.h>
#include <stdint.h>

#define NN 100000      // nodes
#define NE 1600000     // edges
#define INF 256        // in feats
#define HF 128         // hidden feats
#define NC 40          // classes
#define NNP 100352     // NN padded to multiple of 512
#define NB (NNP / 512) // 196 scan blocks

typedef unsigned short ushort_t;
typedef unsigned int uint_t;
typedef __attribute__((ext_vector_type(8))) short short8;   // 8 bf16 (4 VGPR)
typedef __attribute__((ext_vector_type(4))) float f32x4;

__device__ __forceinline__ float bflo(uint_t u) {
    union { uint_t i; float f; } v; v.i = u << 16; return v.f;
}
__device__ __forceinline__ float bfhi(uint_t u) {
    union { uint_t i; float f; } v; v.i = u & 0xffff0000u; return v.f;
}
__device__ __forceinline__ uint_t f2bf(float f) {
    __hip_bfloat16 h = __float2bfloat16(f);
    return (uint_t)*reinterpret_cast<ushort_t*>(&h);
}

// ---- degree histograms + one-time W1 -> fragment-major bf16 ----
// W1f layout: element (k,n) -> (((ks*8+ct)*4+q)*16+ln)*8 + j
// with ks=k/32, q=(k/8)%4, j=k%8, ct=n/16, ln=n%16
__global__ void k_deg(const int* __restrict__ src, const int* __restrict__ dst,
                      int* __restrict__ cs, int* __restrict__ cd,
                      const float* __restrict__ W1, ushort_t* __restrict__ W1f) {
    int i = blockIdx.x * 256 + threadIdx.x;
    if (i < NE) {
        atomicAdd(&cs[src[i]], 1);
        atomicAdd(&cd[dst[i]], 1);
    }
    if (i < INF * HF) {
        int k = i >> 7, n = i & 127;
        int ks = k >> 5, q = (k >> 3) & 3, j = k & 7;
        int ct = n >> 4, ln = n & 15;
        int off = (((ks * 8 + ct) * 4 + q) * 16 + ln) * 8 + j;
        W1f[off] = (ushort_t)f2bf(W1[i]);
    }
}

// ---- scan phase A: per-block sums of cd ----
__global__ void k_scanA(const int* __restrict__ cd, int* __restrict__ blk) {
    __shared__ int s[512];
    int i = blockIdx.x * 512 + threadIdx.x;
    s[threadIdx.x] = (i < NN) ? cd[i] : 0;
    __syncthreads();
    for (int off = 256; off > 0; off >>= 1) {
        if (threadIdx.x < (unsigned)off) s[threadIdx.x] += s[threadIdx.x + off];
        __syncthreads();
    }
    if (threadIdx.x == 0) blk[blockIdx.x] = s[0];
}

// ---- scan phase B: exclusive scan of block sums ----
__global__ void k_scanB(int* __restrict__ blk) {
    if (threadIdx.x == 0) {
        int run = 0;
        for (int b = 0; b < NB; ++b) { int t = blk[b]; blk[b] = run; run += t; }
    }
}

// ---- scan phase C: row_ptr/cursor + isqrt norms (fused) ----
__global__ void k_scanC(const int* __restrict__ cd, const int* __restrict__ blk,
                        const int* __restrict__ cs,
                        int* __restrict__ row_ptr, int* __restrict__ cursor,
                        float* __restrict__ isq_s, float* __restrict__ isq_d) {
    __shared__ int s[512];
    int i = blockIdx.x * 512 + threadIdx.x;
    int v = (i < NN) ? cd[i] : 0;
    s[threadIdx.x] = v;
    __syncthreads();
    for (int off = 1; off < 512; off <<= 1) {
        int t = 0;
        if (threadIdx.x >= (unsigned)off) t = s[threadIdx.x - off];
        __syncthreads();
        s[threadIdx.x] += t;
        __syncthreads();
    }
    int rp = blk[blockIdx.x] + s[threadIdx.x] - v;  // exclusive prefix
    row_ptr[i] = rp;      // row_ptr[NN] == NE
    // norms (before cursor write: cursor aliases cs, read cs first)
    float fs = rsqrtf(fmaxf((float)cs[i], 1.0f));
    float fd = rsqrtf(fmaxf((float)v, 1.0f));
    cursor[i] = rp;
    isq_s[i] = fs;
    isq_d[i] = fd;
}

// ---- counting-sort fill: src ids grouped by dst ----
__global__ void k_fill(const int* __restrict__ src, const int* __restrict__ dst,
                       int* __restrict__ cursor, int* __restrict__ srcs) {
    int e = blockIdx.x * 256 + threadIdx.x;
    if (e < NE) {
        int d = dst[e];
        int pos = atomicAdd(&cursor[d], 1);
        srcs[pos] = src[e];
    }
}

// ---- GEMM1 (MFMA): H[N,128](bf16) = (X[N,256] @ W1) * isq_s[row] ----
__launch_bounds__(256)
__global__ void k_gemm1(const float* __restrict__ X, const ushort_t* __restrict__ W1f,
                        const float* __restrict__ isq_s, ushort_t* __restrict__ H) {
    const int wv = threadIdx.x >> 6;
    const int lane = threadIdx.x & 63;
    const int ln = lane & 15;
    const int q  = lane >> 4;
    const int r0 = blockIdx.x * 64 + wv * 16;
    const int rm = min(r0 + ln, NN - 1);     // A row for this lane (m = ln)

    f32x4 acc[8];
#pragma unroll
    for (int ct = 0; ct < 8; ++ct) acc[ct] = (f32x4){0.f, 0.f, 0.f, 0.f};

    const float* xp = &X[(size_t)rm * INF + q * 8];
    const uint4* wf = (const uint4*)W1f;

    for (int ks = 0; ks < 8; ++ks) {
        float4 xa = *(const float4*)xp;
        float4 xb = *(const float4*)(xp + 4);
        xp += 32;
        short8 af;
        af[0] = (short)f2bf(xa.x); af[1] = (short)f2bf(xa.y);
        af[2] = (short)f2bf(xa.z); af[3] = (short)f2bf(xa.w);
        af[4] = (short)f2bf(xb.x); af[5] = (short)f2bf(xb.y);
        af[6] = (short)f2bf(xb.z); af[7] = (short)f2bf(xb.w);
#pragma unroll
        for (int ct = 0; ct < 8; ++ct) {
            union { uint4 u; short8 s; } bv;
            bv.u = wf[(size_t)(ks * 8 + ct) * 64 + lane];
            acc[ct] = __builtin_amdgcn_mfma_f32_16x16x32_bf16(af, bv.s, acc[ct], 0, 0, 0);
        }
    }

#pragma unroll
    for (int reg = 0; reg < 4; ++reg) {
        int r = r0 + q * 4 + reg;
        if (r < NN) {
            float s = isq_s[r];
#pragma unroll
            for (int ct = 0; ct < 8; ++ct)
                H[(size_t)r * HF + ct * 16 + ln] = (ushort_t)f2bf(acc[ct][reg] * s);
        }
    }
}

// unpack-accumulate one 16B slice (8 bf16 feats) into a[0..7]
#define ACC8(v) { a[0] += bflo((v).x); a[1] += bfhi((v).x); \
                  a[2] += bflo((v).y); a[3] += bfhi((v).y); \
                  a[4] += bflo((v).z); a[5] += bfhi((v).z); \
                  a[6] += bflo((v).w); a[7] += bfhi((v).w); }

// ---- fused layer1-aggregate + layer2 GEMM ----
// Gather restructured for MLP: 16 lanes cover one 256B H row as uint4,
// 4 edge slots per wave-load instruction, 16-edge main tier = 4KB in flight.
__launch_bounds__(256)
__global__ void k_agg1_gemm2(const int* __restrict__ row_ptr, const int* __restrict__ srcs,
                             const uint4* __restrict__ H16, const float* __restrict__ isq_d,
                             const float* __restrict__ isq_s, const float* __restrict__ b1,
                             const float* __restrict__ W2, ushort_t* __restrict__ H2b) {
    __shared__ float w2s[HF * NC];              // 20 KB fp32
    __shared__ __align__(16) float h1s[4][HF];  // 2 KB, one slice per wave
    for (int t = threadIdx.x; t < HF * NC; t += 256) w2s[t] = W2[t];

    const int wv = threadIdx.x >> 6;
    const int lane = threadIdx.x & 63;
    const int grp = lane >> 4;   // edge slot 0..3
    const int gl  = lane & 15;   // uint4 index within 256B row
    const int n = blockIdx.x * 4 + wv;

    float a[8];
#pragma unroll
    for (int k = 0; k < 8; ++k) a[k] = 0.0f;

    if (n < NN) {
        int beg = row_ptr[n], end = row_ptr[n + 1];
        int j = beg;
        // 16 edges/iter: 4 gathers (4 KB) in flight per lane-group set
        for (; j + 16 <= end; j += 16) {
            int sA = srcs[j + grp];
            int sB = srcs[j + 4 + grp];
            int sC = srcs[j + 8 + grp];
            int sD = srcs[j + 12 + grp];
            uint4 vA = H16[(size_t)sA * 16 + gl];
            uint4 vB = H16[(size_t)sB * 16 + gl];
            uint4 vC = H16[(size_t)sC * 16 + gl];
            uint4 vD = H16[(size_t)sD * 16 + gl];
            ACC8(vA); ACC8(vB); ACC8(vC); ACC8(vD);
        }
        for (; j + 8 <= end; j += 8) {
            int sA = srcs[j + grp];
            int sB = srcs[j + 4 + grp];
            uint4 vA = H16[(size_t)sA * 16 + gl];
            uint4 vB = H16[(size_t)sB * 16 + gl];
            ACC8(vA); ACC8(vB);
        }
        for (; j + 4 <= end; j += 4) {
            uint4 v = H16[(size_t)srcs[j + grp] * 16 + gl];
            ACC8(v);
        }
        int r = end - j;                        // 0..3 tail edges
        if (grp < r) {
            uint4 v = H16[(size_t)srcs[j + grp] * 16 + gl];
            ACC8(v);
        }
    }
    // combine the 4 edge-slot partials (lane bits 4 and 5)
#pragma unroll
    for (int k = 0; k < 8; ++k) {
        a[k] += __shfl_xor(a[k], 16);
        a[k] += __shfl_xor(a[k], 32);
    }

    if (n < NN && lane < 16) {
        float sc = isq_d[n];
        float4 ba = ((const float4*)b1)[gl * 2];
        float4 bb = ((const float4*)b1)[gl * 2 + 1];
        float4 ha = { fmaxf(a[0] * sc + ba.x, 0.0f), fmaxf(a[1] * sc + ba.y, 0.0f),
                      fmaxf(a[2] * sc + ba.z, 0.0f), fmaxf(a[3] * sc + ba.w, 0.0f) };
        float4 hb = { fmaxf(a[4] * sc + bb.x, 0.0f), fmaxf(a[5] * sc + bb.y, 0.0f),
                      fmaxf(a[6] * sc + bb.z, 0.0f), fmaxf(a[7] * sc + bb.w, 0.0f) };
        float4* hp = (float4*)&h1s[wv][gl * 8];
        hp[0] = ha; hp[1] = hb;
    }
    __syncthreads();   // uniform: covers W2 staging + h1 slices

    if (n < NN && lane < NC) {
        float acc = 0.0f;
#pragma unroll 8
        for (int k = 0; k < HF; ++k)
            acc += h1s[wv][k] * w2s[k * NC + lane];
        H2b[(size_t)n * NC + lane] = (ushort_t)f2bf(acc * isq_s[n]);
    }
}

// ---- gather2 v2: 10 lanes x uint2 per edge, 6 edges per wave in parallel ----
__global__ void k_gather2(const int* __restrict__ row_ptr, const int* __restrict__ srcs,
                          const uint2* __restrict__ H2b2, const float* __restrict__ isq_d,
                          const float* __restrict__ b2, float* __restrict__ out) {
    __shared__ float4 pt[4][64];     // 4 KB partials
    const int wv = threadIdx.x >> 6;
    const int lane = threadIdx.x & 63;
    const int grp = lane / 10;       // 0..5 active edge slots, 6 = idle lanes 60-63
    const int gl  = lane - grp * 10; // uint2 index within the 80B row
    const int n = blockIdx.x * 4 + wv;

    float a0 = 0.f, a1 = 0.f, a2 = 0.f, a3 = 0.f;
    if (n < NN && grp < 6) {
        int beg = row_ptr[n], end = row_ptr[n + 1];
        int j = beg;
        for (; j + 12 <= end; j += 12) {           // 12 edges in flight
            int eA = j + grp, eB = j + 6 + grp;
            uint2 vA = H2b2[(size_t)srcs[eA] * 10 + gl];
            uint2 vB = H2b2[(size_t)srcs[eB] * 10 + gl];
            a0 += bflo(vA.x) + bflo(vB.x);
            a1 += bfhi(vA.x) + bfhi(vB.x);
            a2 += bflo(vA.y) + bflo(vB.y);
            a3 += bfhi(vA.y) + bfhi(vB.y);
        }
        if (j + 6 <= end) {
            uint2 v = H2b2[(size_t)srcs[j + grp] * 10 + gl];
            a0 += bflo(v.x); a1 += bfhi(v.x);
            a2 += bflo(v.y); a3 += bfhi(v.y);
            j += 6;
        }
        int r = end - j;                            // 0..5 tail edges
        if (grp < r) {
            uint2 v = H2b2[(size_t)srcs[j + grp] * 10 + gl];
            a0 += bflo(v.x); a1 += bfhi(v.x);
            a2 += bflo(v.y); a3 += bfhi(v.y);
        }
    }
    pt[wv][lane] = (float4){a0, a1, a2, a3};
    __syncthreads();

    if (n < NN && lane < 10) {
        float4 s = pt[wv][lane];
#pragma unroll
        for (int g = 1; g < 6; ++g) {
            float4 t = pt[wv][g * 10 + lane];
            s.x += t.x; s.y += t.y; s.z += t.z; s.w += t.w;
        }
        float sc = isq_d[n];
        float4 bv = *(const float4*)&b2[lane * 4];
        float4 o = { s.x * sc + bv.x, s.y * sc + bv.y,
                     s.z * sc + bv.z, s.w * sc + bv.w };
        *(float4*)&out[(size_t)n * NC + lane * 4] = o;
    }
}

extern "C" void kernel_launch(void* const* d_in, const int* in_sizes, int n_in,
                              void* d_out, int out_size, void* d_ws, size_t ws_size,
                              hipStream_t stream) {
    const float* X  = (const float*)d_in[0];
    const int* src  = (const int*)d_in[1];
    const int* dst  = (const int*)d_in[2];
    const float* W1 = (const float*)d_in[3];
    const float* b1 = (const float*)d_in[4];
    const float* W2 = (const float*)d_in[5];
    const float* b2 = (const float*)d_in[6];
    float* out = (float*)d_out;

    // workspace layout in 4-byte words; peak = 10,518,656 words = 40.1 MiB
    int* w = (int*)d_ws;
    int* cs        = w;                         // NNP  (reused as cursor)
    int* cd        = w + NNP;                   // NNP
    float* isq_s   = (float*)(w + 2 * NNP);     // NNP
    float* isq_d   = (float*)(w + 3 * NNP);     // NNP
    int* row_ptr   = w + 4 * NNP;               // NNP (row_ptr[NN] valid)
    int* blk       = w + 5 * NNP;               // 512
    ushort_t* W1f  = (ushort_t*)(w + 5 * NNP + 512);             // 32768 bf16
    int* srcs      = w + 5 * NNP + 512 + 16384; // NE
    ushort_t* H    = (ushort_t*)(w + 5 * NNP + 512 + 16384 + NE);           // N*128 bf16
    ushort_t* H2b  = (ushort_t*)(w + 5 * NNP + 512 + 16384 + NE + 6400000); // N*40 bf16
    int* cursor    = cs;                        // alias: cs consumed inside k_scanC

    hipMemsetAsync(cs, 0, 2 * NNP * sizeof(int), stream);

    // CSR build (dst-grouped) + W1 fragment conversion
    k_deg  <<<(NE + 255) / 256, 256, 0, stream>>>(src, dst, cs, cd, W1, W1f);
    k_scanA<<<NB, 512, 0, stream>>>(cd, blk);
    k_scanB<<<1, 64, 0, stream>>>(blk);
    k_scanC<<<NB, 512, 0, stream>>>(cd, blk, cs, row_ptr, cursor, isq_s, isq_d);
    k_fill <<<(NE + 255) / 256, 256, 0, stream>>>(src, dst, cursor, srcs);

    // layer 1 GEMM (MFMA)
    k_gemm1<<<(NN + 63) / 64, 256, 0, stream>>>(X, W1f, isq_s, H);

    // fused: layer-1 aggregate + bias/relu + layer-2 GEMM -> bf16 H2
    k_agg1_gemm2<<<(NN + 3) / 4, 256, 0, stream>>>(row_ptr, srcs, (const uint4*)H,
                                                   isq_d, isq_s, b1, W2, H2b);

    // layer-2 aggregate + bias -> fp32 out
    k_gather2<<<(NN + 3) / 4, 256, 0, stream>>>(row_ptr, srcs, (const uint2*)H2b,
                                                isq_d, b2, out);
}

// Round 2
// 546.351 us; speedup vs baseline: 1.1380x; 1.0939x over previous
//
#include <hip/hip_runtime.h>
#include <hip/hip_bf16.h>
#include <stdint.h>

#define NN 100000      // nodes
#define NE 1600000     // edges
#define INF 256        // in feats
#define HF 128         // hidden feats
#define NC 40          // classes
#define NNP 100352     // NN padded to multiple of 512
#define NB (NNP / 512) // 196 scan blocks

typedef unsigned short ushort_t;
typedef unsigned int uint_t;
typedef __attribute__((ext_vector_type(8))) short short8;   // 8 bf16 (4 VGPR)
typedef __attribute__((ext_vector_type(4))) float f32x4;

__device__ __forceinline__ float bflo(uint_t u) {
    union { uint_t i; float f; } v; v.i = u << 16; return v.f;
}
__device__ __forceinline__ float bfhi(uint_t u) {
    union { uint_t i; float f; } v; v.i = u & 0xffff0000u; return v.f;
}
__device__ __forceinline__ uint_t f2bf(float f) {
    __hip_bfloat16 h = __float2bfloat16(f);
    return (uint_t)*reinterpret_cast<ushort_t*>(&h);
}

// ---- degree histograms + one-time W1/W2 -> fragment-major bf16 ----
// W1f layout: element (k,n) -> (((ks*8+ct)*4+q)*16+ln)*8 + j   (ks=k/32,q=(k/8)%4,j=k%8,ct=n/16,ln=n%16)
// W2f layout: K=128, N padded 40->48: (((ks*3+ct)*4+q)*16+ln)*8 + j
__global__ void k_deg(const int* __restrict__ src, const int* __restrict__ dst,
                      int* __restrict__ cs, int* __restrict__ cd,
                      const float* __restrict__ W1, ushort_t* __restrict__ W1f,
                      const float* __restrict__ W2, ushort_t* __restrict__ W2f) {
    int i = blockIdx.x * 256 + threadIdx.x;
    if (i < NE) {
        atomicAdd(&cs[src[i]], 1);
        atomicAdd(&cd[dst[i]], 1);
    }
    if (i < INF * HF) {
        int k = i >> 7, n = i & 127;
        int ks = k >> 5, q = (k >> 3) & 3, j = k & 7;
        int ct = n >> 4, ln = n & 15;
        int off = (((ks * 8 + ct) * 4 + q) * 16 + ln) * 8 + j;
        W1f[off] = (ushort_t)f2bf(W1[i]);
    }
    if (i < HF * 48) {
        int k = i / 48, n = i % 48;
        int ks = k >> 5, q = (k >> 3) & 3, j = k & 7;
        int ct = n >> 4, ln = n & 15;
        int off = (((ks * 3 + ct) * 4 + q) * 16 + ln) * 8 + j;
        float v = (n < NC) ? W2[k * NC + n] : 0.0f;
        W2f[off] = (ushort_t)f2bf(v);
    }
}

// ---- scan phase A: per-block sums of cd ----
__global__ void k_scanA(const int* __restrict__ cd, int* __restrict__ blk) {
    __shared__ int s[512];
    int i = blockIdx.x * 512 + threadIdx.x;
    s[threadIdx.x] = (i < NN) ? cd[i] : 0;
    __syncthreads();
    for (int off = 256; off > 0; off >>= 1) {
        if (threadIdx.x < (unsigned)off) s[threadIdx.x] += s[threadIdx.x + off];
        __syncthreads();
    }
    if (threadIdx.x == 0) blk[blockIdx.x] = s[0];
}

// ---- scan phase B: exclusive scan of block sums (parallel, 1 block) ----
__global__ void k_scanB(int* __restrict__ blk) {
    __shared__ int s[256];
    int t = threadIdx.x;
    int v = (t < NB) ? blk[t] : 0;
    s[t] = v;
    __syncthreads();
    for (int off = 1; off < 256; off <<= 1) {
        int tv = (t >= off) ? s[t - off] : 0;
        __syncthreads();
        s[t] += tv;
        __syncthreads();
    }
    if (t < NB) blk[t] = s[t] - v;   // exclusive
}

// ---- scan phase C: row_ptr/cursor + isqrt norms (fused) ----
__global__ void k_scanC(const int* __restrict__ cd, const int* __restrict__ blk,
                        const int* __restrict__ cs,
                        int* __restrict__ row_ptr, int* __restrict__ cursor,
                        float* __restrict__ isq_s, float* __restrict__ isq_d) {
    __shared__ int s[512];
    int i = blockIdx.x * 512 + threadIdx.x;
    int v = (i < NN) ? cd[i] : 0;
    s[threadIdx.x] = v;
    __syncthreads();
    for (int off = 1; off < 512; off <<= 1) {
        int t = 0;
        if (threadIdx.x >= (unsigned)off) t = s[threadIdx.x - off];
        __syncthreads();
        s[threadIdx.x] += t;
        __syncthreads();
    }
    int rp = blk[blockIdx.x] + s[threadIdx.x] - v;  // exclusive prefix
    row_ptr[i] = rp;      // row_ptr[NN] == NE
    float fs = rsqrtf(fmaxf((float)cs[i], 1.0f));
    float fd = rsqrtf(fmaxf((float)v, 1.0f));
    cursor[i] = rp;
    isq_s[i] = fs;
    isq_d[i] = fd;
}

// ---- counting-sort fill: src ids grouped by dst ----
__global__ void k_fill(const int* __restrict__ src, const int* __restrict__ dst,
                       int* __restrict__ cursor, int* __restrict__ srcs) {
    int e = blockIdx.x * 256 + threadIdx.x;
    if (e < NE) {
        int d = dst[e];
        int pos = atomicAdd(&cursor[d], 1);
        srcs[pos] = src[e];
    }
}

// ---- GEMM1 (MFMA): H[N,128](bf16) = (X[N,256] @ W1) * isq_s[row] ----
__launch_bounds__(256)
__global__ void k_gemm1(const float* __restrict__ X, const ushort_t* __restrict__ W1f,
                        const float* __restrict__ isq_s, ushort_t* __restrict__ H) {
    const int wv = threadIdx.x >> 6;
    const int lane = threadIdx.x & 63;
    const int ln = lane & 15;
    const int q  = lane >> 4;
    const int r0 = blockIdx.x * 64 + wv * 16;
    const int rm = min(r0 + ln, NN - 1);     // A row for this lane (m = ln)

    f32x4 acc[8];
#pragma unroll
    for (int ct = 0; ct < 8; ++ct) acc[ct] = (f32x4){0.f, 0.f, 0.f, 0.f};

    const float* xp = &X[(size_t)rm * INF + q * 8];
    const uint4* wf = (const uint4*)W1f;

    for (int ks = 0; ks < 8; ++ks) {
        float4 xa = *(const float4*)xp;
        float4 xb = *(const float4*)(xp + 4);
        xp += 32;
        short8 af;
        af[0] = (short)f2bf(xa.x); af[1] = (short)f2bf(xa.y);
        af[2] = (short)f2bf(xa.z); af[3] = (short)f2bf(xa.w);
        af[4] = (short)f2bf(xb.x); af[5] = (short)f2bf(xb.y);
        af[6] = (short)f2bf(xb.z); af[7] = (short)f2bf(xb.w);
#pragma unroll
        for (int ct = 0; ct < 8; ++ct) {
            union { uint4 u; short8 s; } bv;
            bv.u = wf[(size_t)(ks * 8 + ct) * 64 + lane];
            acc[ct] = __builtin_amdgcn_mfma_f32_16x16x32_bf16(af, bv.s, acc[ct], 0, 0, 0);
        }
    }

#pragma unroll
    for (int reg = 0; reg < 4; ++reg) {
        int r = r0 + q * 4 + reg;
        if (r < NN) {
            float s = isq_s[r];
#pragma unroll
            for (int ct = 0; ct < 8; ++ct)
                H[(size_t)r * HF + ct * 16 + ln] = (ushort_t)f2bf(acc[ct][reg] * s);
        }
    }
}

// unpack-accumulate one 16B slice (8 bf16 feats) into a[0..7]
#define ACC8(v) { a[0] += bflo((v).x); a[1] += bfhi((v).x); \
                  a[2] += bflo((v).y); a[3] += bfhi((v).y); \
                  a[4] += bflo((v).z); a[5] += bfhi((v).z); \
                  a[6] += bflo((v).w); a[7] += bfhi((v).w); }

// ---- fused layer1-aggregate + layer2 GEMM (MFMA form) ----
// Block = 16 nodes. Each wave aggregates 4 nodes (16 lanes x uint4 per row,
// 4 edge slots per load instr). h1 packed bf16 into a 4KB XOR-swizzled LDS
// tile; waves 0-2 then do 4 MFMA each (M=16 nodes, N=16 cols, K=128) with
// B-frags (W2f) read straight from global (L2-hot, no staging).
__launch_bounds__(256)
__global__ void k_agg1_gemm2(const int* __restrict__ row_ptr, const int* __restrict__ srcs,
                             const uint4* __restrict__ H16, const float* __restrict__ isq_d,
                             const float* __restrict__ isq_s, const float* __restrict__ b1,
                             const ushort_t* __restrict__ W2f, ushort_t* __restrict__ H2b) {
    __shared__ uint4 h1s[16][16];   // 4 KB: [local node][swizzled k-slice]
    const int wv = threadIdx.x >> 6;
    const int lane = threadIdx.x & 63;
    const int grp = lane >> 4;   // edge slot 0..3
    const int gl  = lane & 15;   // uint4 index within 256B row
    const int n0 = blockIdx.x * 16;   // 6250 blocks * 16 == NN exactly

    const float4 bva = ((const float4*)b1)[gl * 2];
    const float4 bvb = ((const float4*)b1)[gl * 2 + 1];

    for (int ni = 0; ni < 4; ++ni) {
        const int rl = wv * 4 + ni;        // local node 0..15
        const int n = n0 + rl;
        float a[8];
#pragma unroll
        for (int k = 0; k < 8; ++k) a[k] = 0.0f;

        int beg = row_ptr[n], end = row_ptr[n + 1];
        int j = beg;
        for (; j + 16 <= end; j += 16) {   // 16 edges/iter, 4 KB in flight
            int sA = srcs[j + grp];
            int sB = srcs[j + 4 + grp];
            int sC = srcs[j + 8 + grp];
            int sD = srcs[j + 12 + grp];
            uint4 vA = H16[(size_t)sA * 16 + gl];
            uint4 vB = H16[(size_t)sB * 16 + gl];
            uint4 vC = H16[(size_t)sC * 16 + gl];
            uint4 vD = H16[(size_t)sD * 16 + gl];
            ACC8(vA); ACC8(vB); ACC8(vC); ACC8(vD);
        }
        for (; j + 8 <= end; j += 8) {
            int sA = srcs[j + grp];
            int sB = srcs[j + 4 + grp];
            uint4 vA = H16[(size_t)sA * 16 + gl];
            uint4 vB = H16[(size_t)sB * 16 + gl];
            ACC8(vA); ACC8(vB);
        }
        for (; j + 4 <= end; j += 4) {
            uint4 v = H16[(size_t)srcs[j + grp] * 16 + gl];
            ACC8(v);
        }
        int r = end - j;                   // 0..3 tail edges
        if (grp < r) {
            uint4 v = H16[(size_t)srcs[j + grp] * 16 + gl];
            ACC8(v);
        }
        // combine the 4 edge-slot partials (lane bits 4 and 5)
#pragma unroll
        for (int k = 0; k < 8; ++k) {
            a[k] += __shfl_xor(a[k], 16);
            a[k] += __shfl_xor(a[k], 32);
        }
        if (lane < 16) {
            float sc = isq_d[n];
            uint_t p0 = f2bf(fmaxf(a[0] * sc + bva.x, 0.0f))
                      | (f2bf(fmaxf(a[1] * sc + bva.y, 0.0f)) << 16);
            uint_t p1 = f2bf(fmaxf(a[2] * sc + bva.z, 0.0f))
                      | (f2bf(fmaxf(a[3] * sc + bva.w, 0.0f)) << 16);
            uint_t p2 = f2bf(fmaxf(a[4] * sc + bvb.x, 0.0f))
                      | (f2bf(fmaxf(a[5] * sc + bvb.y, 0.0f)) << 16);
            uint_t p3 = f2bf(fmaxf(a[6] * sc + bvb.z, 0.0f))
                      | (f2bf(fmaxf(a[7] * sc + bvb.w, 0.0f)) << 16);
            h1s[rl][gl ^ rl] = (uint4){p0, p1, p2, p3};   // XOR-swizzle vs row
        }
    }
    __syncthreads();

    // GEMM2: waves 0-2 each own one 16-col tile (N padded 40->48)
    if (wv < 3) {
        const int q = grp;     // lane>>4
        const int ln = gl;     // lane&15; A row (= local node) for this lane
        f32x4 acc = (f32x4){0.f, 0.f, 0.f, 0.f};
        const uint4* wf = (const uint4*)W2f;
#pragma unroll
        for (int ks = 0; ks < 4; ++ks) {
            union { uint4 u; short8 s; } av, bv;
            av.u = h1s[ln][(ks * 4 + q) ^ ln];            // matching swizzle
            bv.u = wf[(size_t)(ks * 3 + wv) * 64 + lane];
            acc = __builtin_amdgcn_mfma_f32_16x16x32_bf16(av.s, bv.s, acc, 0, 0, 0);
        }
        int c = wv * 16 + ln;
        if (c < NC) {
#pragma unroll
            for (int reg = 0; reg < 4; ++reg) {
                int rg = n0 + q * 4 + reg;
                H2b[(size_t)rg * NC + c] = (ushort_t)f2bf(acc[reg] * isq_s[rg]);
            }
        }
    }
}

// ---- gather2 v2: 10 lanes x uint2 per edge, 6 edges per wave in parallel ----
__global__ void k_gather2(const int* __restrict__ row_ptr, const int* __restrict__ srcs,
                          const uint2* __restrict__ H2b2, const float* __restrict__ isq_d,
                          const float* __restrict__ b2, float* __restrict__ out) {
    __shared__ float4 pt[4][64];     // 4 KB partials
    const int wv = threadIdx.x >> 6;
    const int lane = threadIdx.x & 63;
    const int grp = lane / 10;       // 0..5 active edge slots, 6 = idle lanes 60-63
    const int gl  = lane - grp * 10; // uint2 index within the 80B row
    const int n = blockIdx.x * 4 + wv;

    float a0 = 0.f, a1 = 0.f, a2 = 0.f, a3 = 0.f;
    if (n < NN && grp < 6) {
        int beg = row_ptr[n], end = row_ptr[n + 1];
        int j = beg;
        for (; j + 12 <= end; j += 12) {           // 12 edges in flight
            int eA = j + grp, eB = j + 6 + grp;
            uint2 vA = H2b2[(size_t)srcs[eA] * 10 + gl];
            uint2 vB = H2b2[(size_t)srcs[eB] * 10 + gl];
            a0 += bflo(vA.x) + bflo(vB.x);
            a1 += bfhi(vA.x) + bfhi(vB.x);
            a2 += bflo(vA.y) + bflo(vB.y);
            a3 += bfhi(vA.y) + bfhi(vB.y);
        }
        if (j + 6 <= end) {
            uint2 v = H2b2[(size_t)srcs[j + grp] * 10 + gl];
            a0 += bflo(v.x); a1 += bfhi(v.x);
            a2 += bflo(v.y); a3 += bfhi(v.y);
            j += 6;
        }
        int r = end - j;                            // 0..5 tail edges
        if (grp < r) {
            uint2 v = H2b2[(size_t)srcs[j + grp] * 10 + gl];
            a0 += bflo(v.x); a1 += bfhi(v.x);
            a2 += bflo(v.y); a3 += bfhi(v.y);
        }
    }
    pt[wv][lane] = (float4){a0, a1, a2, a3};
    __syncthreads();

    if (n < NN && lane < 10) {
        float4 s = pt[wv][lane];
#pragma unroll
        for (int g = 1; g < 6; ++g) {
            float4 t = pt[wv][g * 10 + lane];
            s.x += t.x; s.y += t.y; s.z += t.z; s.w += t.w;
        }
        float sc = isq_d[n];
        float4 bv = *(const float4*)&b2[lane * 4];
        float4 o = { s.x * sc + bv.x, s.y * sc + bv.y,
                     s.z * sc + bv.z, s.w * sc + bv.w };
        *(float4*)&out[(size_t)n * NC + lane * 4] = o;
    }
}

extern "C" void kernel_launch(void* const* d_in, const int* in_sizes, int n_in,
                              void* d_out, int out_size, void* d_ws, size_t ws_size,
                              hipStream_t stream) {
    const float* X  = (const float*)d_in[0];
    const int* src  = (const int*)d_in[1];
    const int* dst  = (const int*)d_in[2];
    const float* W1 = (const float*)d_in[3];
    const float* b1 = (const float*)d_in[4];
    const float* W2 = (const float*)d_in[5];
    const float* b2 = (const float*)d_in[6];
    float* out = (float*)d_out;

    // workspace layout in 4-byte words; peak ~= 40.1 MiB (+12KB W2f)
    int* w = (int*)d_ws;
    int* cs        = w;                         // NNP  (reused as cursor)
    int* cd        = w + NNP;                   // NNP
    float* isq_s   = (float*)(w + 2 * NNP);     // NNP
    float* isq_d   = (float*)(w + 3 * NNP);     // NNP
    int* row_ptr   = w + 4 * NNP;               // NNP (row_ptr[NN] valid)
    int* blk       = w + 5 * NNP;               // 512
    ushort_t* W1f  = (ushort_t*)(w + 5 * NNP + 512);             // 32768 bf16
    ushort_t* W2f  = (ushort_t*)(w + 5 * NNP + 512 + 16384);     // 6144 bf16
    int* srcs      = w + 5 * NNP + 512 + 16384 + 3072;           // NE
    ushort_t* H    = (ushort_t*)(w + 5 * NNP + 512 + 16384 + 3072 + NE);           // N*128 bf16
    ushort_t* H2b  = (ushort_t*)(w + 5 * NNP + 512 + 16384 + 3072 + NE + 6400000); // N*40 bf16
    int* cursor    = cs;                        // alias: cs consumed inside k_scanC

    hipMemsetAsync(cs, 0, 2 * NNP * sizeof(int), stream);

    // CSR build (dst-grouped) + W1/W2 fragment conversion
    k_deg  <<<(NE + 255) / 256, 256, 0, stream>>>(src, dst, cs, cd, W1, W1f, W2, W2f);
    k_scanA<<<NB, 512, 0, stream>>>(cd, blk);
    k_scanB<<<1, 256, 0, stream>>>(blk);
    k_scanC<<<NB, 512, 0, stream>>>(cd, blk, cs, row_ptr, cursor, isq_s, isq_d);
    k_fill <<<(NE + 255) / 256, 256, 0, stream>>>(src, dst, cursor, srcs);

    // layer 1 GEMM (MFMA)
    k_gemm1<<<(NN + 63) / 64, 256, 0, stream>>>(X, W1f, isq_s, H);

    // fused: layer-1 aggregate + bias/relu + layer-2 GEMM (MFMA) -> bf16 H2
    k_agg1_gemm2<<<NN / 16, 256, 0, stream>>>(row_ptr, srcs, (const uint4*)H,
                                              isq_d, isq_s, b1, W2f, H2b);

    // layer-2 aggregate + bias -> fp32 out
    k_gather2<<<(NN + 3) / 4, 256, 0, stream>>>(row_ptr, srcs, (const uint2*)H2b,
                                                isq_d, b2, out);
}

// Round 3
// 403.443 us; speedup vs baseline: 1.5411x; 1.3542x over previous
//
#include <hip/hip_runtime.h>
#include <hip/hip_bf16.h>
#include <stdint.h>

#define NN 100000      // nodes
#define NE 1600000     // edges
#define INF 256        // in feats
#define HF 128         // hidden feats
#define NC 40          // classes
#define NNP 100352     // NN padded to multiple of 512
#define NBUK 784       // NNP / 128 coarse buckets
#define BKSH 7         // bucket = node >> 7 (128 nodes per bucket)
#define NBLK 128       // blocks for bcount / bfill
#define CHUNK 12500    // edges per block (128 * 12500 == NE)

typedef unsigned short ushort_t;
typedef unsigned int uint_t;
typedef unsigned char uchar_t;
typedef __attribute__((ext_vector_type(8))) short short8;   // 8 bf16 (4 VGPR)
typedef __attribute__((ext_vector_type(4))) float f32x4;

__device__ __forceinline__ float bflo(uint_t u) {
    union { uint_t i; float f; } v; v.i = u << 16; return v.f;
}
__device__ __forceinline__ float bfhi(uint_t u) {
    union { uint_t i; float f; } v; v.i = u & 0xffff0000u; return v.f;
}
__device__ __forceinline__ uint_t f2bf(float f) {
    __hip_bfloat16 h = __float2bfloat16(f);
    return (uint_t)*reinterpret_cast<ushort_t*>(&h);
}

// ---- bucket counts (LDS hist, coalesced flush) + W1/W2 fragment conversion ----
// W1f layout: (k,n) -> (((ks*8+ct)*4+q)*16+ln)*8 + j  (ks=k/32,q=(k/8)%4,j=k%8,ct=n/16,ln=n%15+1... ln=n&15)
// W2f layout: K=128, N padded 40->48: (((ks*3+ct)*4+q)*16+ln)*8 + j
__launch_bounds__(256)
__global__ void k_bcount(const int* __restrict__ src, const int* __restrict__ dst,
                         uint_t* __restrict__ countsA, uint_t* __restrict__ countsB,
                         const float* __restrict__ W1, ushort_t* __restrict__ W1f,
                         const float* __restrict__ W2, ushort_t* __restrict__ W2f) {
    __shared__ uint_t hA[NBUK], hB[NBUK];
    for (int t = threadIdx.x; t < NBUK; t += 256) { hA[t] = 0; hB[t] = 0; }

    // fused one-time weight conversion (grid is exactly 32768 threads)
    int i = blockIdx.x * 256 + threadIdx.x;
    {
        int k = i >> 7, n = i & 127;
        int ks = k >> 5, q = (k >> 3) & 3, j = k & 7;
        int ct = n >> 4, ln = n & 15;
        W1f[(((ks * 8 + ct) * 4 + q) * 16 + ln) * 8 + j] = (ushort_t)f2bf(W1[i]);
    }
    if (i < HF * 48) {
        int k = i / 48, n = i % 48;
        int ks = k >> 5, q = (k >> 3) & 3, j = k & 7;
        int ct = n >> 4, ln = n & 15;
        float v = (n < NC) ? W2[k * NC + n] : 0.0f;
        W2f[(((ks * 3 + ct) * 4 + q) * 16 + ln) * 8 + j] = (ushort_t)f2bf(v);
    }
    __syncthreads();

    const int beg = blockIdx.x * CHUNK, end = beg + CHUNK;
    for (int e = beg + threadIdx.x; e < end; e += 256) {
        atomicAdd(&hA[(uint_t)dst[e] >> BKSH], 1u);
        atomicAdd(&hB[(uint_t)src[e] >> BKSH], 1u);
    }
    __syncthreads();
    for (int t = threadIdx.x; t < NBUK; t += 256) {
        if (hA[t]) atomicAdd(&countsA[t], hA[t]);
        if (hB[t]) atomicAdd(&countsB[t], hB[t]);
    }
}

// ---- exclusive scan of both bucket-count arrays; init bases + cursors ----
__global__ void k_bscan(const uint_t* __restrict__ countsA, const uint_t* __restrict__ countsB,
                        uint_t* __restrict__ basesA, uint_t* __restrict__ basesB,
                        uint_t* __restrict__ cursA, uint_t* __restrict__ cursB) {
    __shared__ uint_t s[1024];
    const int t = threadIdx.x;
    uint_t v = (t < NBUK) ? countsA[t] : 0;
    s[t] = v; __syncthreads();
    for (int off = 1; off < 1024; off <<= 1) {
        uint_t tv = (t >= off) ? s[t - off] : 0;
        __syncthreads();
        s[t] += tv;
        __syncthreads();
    }
    if (t < NBUK) { uint_t e = s[t] - v; basesA[t] = e; cursA[t] = e; }
    if (t == 0) basesA[NBUK] = NE;
    __syncthreads();
    v = (t < NBUK) ? countsB[t] : 0;
    s[t] = v; __syncthreads();
    for (int off = 1; off < 1024; off <<= 1) {
        uint_t tv = (t >= off) ? s[t - off] : 0;
        __syncthreads();
        s[t] += tv;
        __syncthreads();
    }
    if (t < NBUK) { uint_t e = s[t] - v; basesB[t] = e; cursB[t] = e; }
    if (t == 0) basesB[NBUK] = NE;
}

// ---- bucket scatter: per-block LDS hist, one cursor claim per (block,bucket),
//      then plain cached stores (combine in L2 — no device atomics per edge) ----
__launch_bounds__(256)
__global__ void k_bfill(const int* __restrict__ src, const int* __restrict__ dst,
                        uint_t* __restrict__ cursA, uint_t* __restrict__ cursB,
                        uint_t* __restrict__ edgesA, uchar_t* __restrict__ bytesB) {
    __shared__ uint_t hA[NBUK], hB[NBUK];
    for (int t = threadIdx.x; t < NBUK; t += 256) { hA[t] = 0; hB[t] = 0; }
    __syncthreads();
    const int beg = blockIdx.x * CHUNK, end = beg + CHUNK;
    for (int e = beg + threadIdx.x; e < end; e += 256) {
        atomicAdd(&hA[(uint_t)dst[e] >> BKSH], 1u);
        atomicAdd(&hB[(uint_t)src[e] >> BKSH], 1u);
    }
    __syncthreads();
    for (int t = threadIdx.x; t < NBUK; t += 256) {
        uint_t c = hA[t];
        hA[t] = c ? atomicAdd(&cursA[t], c) : 0;
        c = hB[t];
        hB[t] = c ? atomicAdd(&cursB[t], c) : 0;
    }
    __syncthreads();
    for (int e = beg + threadIdx.x; e < end; e += 256) {
        uint_t d = (uint_t)dst[e], s = (uint_t)src[e];
        uint_t pA = atomicAdd(&hA[d >> BKSH], 1u);     // LDS cursor
        edgesA[pA] = ((d & 127u) << 17) | s;           // 24-bit packed (dstLow, src)
        uint_t pB = atomicAdd(&hB[s >> BKSH], 1u);     // LDS cursor
        bytesB[pB] = (uchar_t)(s & 127u);
    }
}

// ---- per-bucket finish: fine histogram -> row_ptr/isq_d, local counting
//      sort -> srcs; plus src-side byte histogram -> isq_s ----
__launch_bounds__(256)
__global__ void k_bfinish(const uint_t* __restrict__ basesA, const uint_t* __restrict__ basesB,
                          const uint_t* __restrict__ edgesA, const uchar_t* __restrict__ bytesB,
                          int* __restrict__ row_ptr, int* __restrict__ srcs,
                          float* __restrict__ isq_d, float* __restrict__ isq_s) {
    __shared__ uint_t h[128], sc[128], cur[128];
    const int b = blockIdx.x, t = threadIdx.x;
    const uint_t beg = basesA[b], end = basesA[b + 1];
    if (t < 128) h[t] = 0;
    __syncthreads();
    for (uint_t e = beg + t; e < end; e += 256)
        atomicAdd(&h[(edgesA[e] >> 17) & 127u], 1u);
    __syncthreads();
    uint_t v = (t < 128) ? h[t] : 0;
    if (t < 128) sc[t] = v;
    __syncthreads();
    for (int off = 1; off < 128; off <<= 1) {
        uint_t tv = (t >= off && t < 128) ? sc[t - off] : 0;
        __syncthreads();
        if (t < 128) sc[t] += tv;
        __syncthreads();
    }
    if (t < 128) {
        uint_t excl = sc[t] - v;
        row_ptr[b * 128 + t] = (int)(beg + excl);
        isq_d[b * 128 + t] = rsqrtf(fmaxf((float)v, 1.0f));
        cur[t] = excl;
    }
    __syncthreads();
    for (uint_t e = beg + t; e < end; e += 256) {
        uint_t u = edgesA[e];
        uint_t p = atomicAdd(&cur[(u >> 17) & 127u], 1u);
        srcs[beg + p] = (int)(u & 0x1FFFFu);
    }
    __syncthreads();
    if (t < 128) h[t] = 0;
    __syncthreads();
    const uint_t begB = basesB[b], endB = basesB[b + 1];
    for (uint_t e = begB + t; e < endB; e += 256)
        atomicAdd(&h[bytesB[e]], 1u);
    __syncthreads();
    if (t < 128) isq_s[b * 128 + t] = rsqrtf(fmaxf((float)h[t], 1.0f));
}

// ---- GEMM1 (MFMA): H[N,128](bf16) = (X[N,256] @ W1) * isq_s[row] ----
__launch_bounds__(256)
__global__ void k_gemm1(const float* __restrict__ X, const ushort_t* __restrict__ W1f,
                        const float* __restrict__ isq_s, ushort_t* __restrict__ H) {
    const int wv = threadIdx.x >> 6;
    const int lane = threadIdx.x & 63;
    const int ln = lane & 15;
    const int q  = lane >> 4;
    const int r0 = blockIdx.x * 64 + wv * 16;
    const int rm = min(r0 + ln, NN - 1);     // A row for this lane (m = ln)

    f32x4 acc[8];
#pragma unroll
    for (int ct = 0; ct < 8; ++ct) acc[ct] = (f32x4){0.f, 0.f, 0.f, 0.f};

    const float* xp = &X[(size_t)rm * INF + q * 8];
    const uint4* wf = (const uint4*)W1f;

    for (int ks = 0; ks < 8; ++ks) {
        float4 xa = *(const float4*)xp;
        float4 xb = *(const float4*)(xp + 4);
        xp += 32;
        short8 af;
        af[0] = (short)f2bf(xa.x); af[1] = (short)f2bf(xa.y);
        af[2] = (short)f2bf(xa.z); af[3] = (short)f2bf(xa.w);
        af[4] = (short)f2bf(xb.x); af[5] = (short)f2bf(xb.y);
        af[6] = (short)f2bf(xb.z); af[7] = (short)f2bf(xb.w);
#pragma unroll
        for (int ct = 0; ct < 8; ++ct) {
            union { uint4 u; short8 s; } bv;
            bv.u = wf[(size_t)(ks * 8 + ct) * 64 + lane];
            acc[ct] = __builtin_amdgcn_mfma_f32_16x16x32_bf16(af, bv.s, acc[ct], 0, 0, 0);
        }
    }

#pragma unroll
    for (int reg = 0; reg < 4; ++reg) {
        int r = r0 + q * 4 + reg;
        if (r < NN) {
            float s = isq_s[r];
#pragma unroll
            for (int ct = 0; ct < 8; ++ct)
                H[(size_t)r * HF + ct * 16 + ln] = (ushort_t)f2bf(acc[ct][reg] * s);
        }
    }
}

// unpack-accumulate one 16B slice (8 bf16 feats) into a[0..7]
#define ACC8(v) { a[0] += bflo((v).x); a[1] += bfhi((v).x); \
                  a[2] += bflo((v).y); a[3] += bfhi((v).y); \
                  a[4] += bflo((v).z); a[5] += bfhi((v).z); \
                  a[6] += bflo((v).w); a[7] += bfhi((v).w); }

// ---- fused layer1-aggregate + layer2 GEMM (MFMA form) ----
__launch_bounds__(256)
__global__ void k_agg1_gemm2(const int* __restrict__ row_ptr, const int* __restrict__ srcs,
                             const uint4* __restrict__ H16, const float* __restrict__ isq_d,
                             const float* __restrict__ isq_s, const float* __restrict__ b1,
                             const ushort_t* __restrict__ W2f, ushort_t* __restrict__ H2b) {
    __shared__ uint4 h1s[16][16];   // 4 KB: [local node][swizzled k-slice]
    const int wv = threadIdx.x >> 6;
    const int lane = threadIdx.x & 63;
    const int grp = lane >> 4;   // edge slot 0..3
    const int gl  = lane & 15;   // uint4 index within 256B row
    const int n0 = blockIdx.x * 16;   // 6250 blocks * 16 == NN exactly

    const float4 bva = ((const float4*)b1)[gl * 2];
    const float4 bvb = ((const float4*)b1)[gl * 2 + 1];

    for (int ni = 0; ni < 4; ++ni) {
        const int rl = wv * 4 + ni;        // local node 0..15
        const int n = n0 + rl;
        float a[8];
#pragma unroll
        for (int k = 0; k < 8; ++k) a[k] = 0.0f;

        int beg = row_ptr[n], end = row_ptr[n + 1];
        int j = beg;
        for (; j + 16 <= end; j += 16) {   // 16 edges/iter, 4 KB in flight
            int sA = srcs[j + grp];
            int sB = srcs[j + 4 + grp];
            int sC = srcs[j + 8 + grp];
            int sD = srcs[j + 12 + grp];
            uint4 vA = H16[(size_t)sA * 16 + gl];
            uint4 vB = H16[(size_t)sB * 16 + gl];
            uint4 vC = H16[(size_t)sC * 16 + gl];
            uint4 vD = H16[(size_t)sD * 16 + gl];
            ACC8(vA); ACC8(vB); ACC8(vC); ACC8(vD);
        }
        for (; j + 8 <= end; j += 8) {
            int sA = srcs[j + grp];
            int sB = srcs[j + 4 + grp];
            uint4 vA = H16[(size_t)sA * 16 + gl];
            uint4 vB = H16[(size_t)sB * 16 + gl];
            ACC8(vA); ACC8(vB);
        }
        for (; j + 4 <= end; j += 4) {
            uint4 v = H16[(size_t)srcs[j + grp] * 16 + gl];
            ACC8(v);
        }
        int r = end - j;                   // 0..3 tail edges
        if (grp < r) {
            uint4 v = H16[(size_t)srcs[j + grp] * 16 + gl];
            ACC8(v);
        }
        // combine the 4 edge-slot partials (lane bits 4 and 5)
#pragma unroll
        for (int k = 0; k < 8; ++k) {
            a[k] += __shfl_xor(a[k], 16);
            a[k] += __shfl_xor(a[k], 32);
        }
        if (lane < 16) {
            float sc = isq_d[n];
            uint_t p0 = f2bf(fmaxf(a[0] * sc + bva.x, 0.0f))
                      | (f2bf(fmaxf(a[1] * sc + bva.y, 0.0f)) << 16);
            uint_t p1 = f2bf(fmaxf(a[2] * sc + bva.z, 0.0f))
                      | (f2bf(fmaxf(a[3] * sc + bva.w, 0.0f)) << 16);
            uint_t p2 = f2bf(fmaxf(a[4] * sc + bvb.x, 0.0f))
                      | (f2bf(fmaxf(a[5] * sc + bvb.y, 0.0f)) << 16);
            uint_t p3 = f2bf(fmaxf(a[6] * sc + bvb.z, 0.0f))
                      | (f2bf(fmaxf(a[7] * sc + bvb.w, 0.0f)) << 16);
            h1s[rl][gl ^ rl] = (uint4){p0, p1, p2, p3};   // XOR-swizzle vs row
        }
    }
    __syncthreads();

    // GEMM2: waves 0-2 each own one 16-col tile (N padded 40->48)
    if (wv < 3) {
        const int q = grp;     // lane>>4
        const int ln = gl;     // lane&15; A row (= local node) for this lane
        f32x4 acc = (f32x4){0.f, 0.f, 0.f, 0.f};
        const uint4* wf = (const uint4*)W2f;
#pragma unroll
        for (int ks = 0; ks < 4; ++ks) {
            union { uint4 u; short8 s; } av, bv;
            av.u = h1s[ln][(ks * 4 + q) ^ ln];            // matching swizzle
            bv.u = wf[(size_t)(ks * 3 + wv) * 64 + lane];
            acc = __builtin_amdgcn_mfma_f32_16x16x32_bf16(av.s, bv.s, acc, 0, 0, 0);
        }
        int c = wv * 16 + ln;
        if (c < NC) {
#pragma unroll
            for (int reg = 0; reg < 4; ++reg) {
                int rg = n0 + q * 4 + reg;
                H2b[(size_t)rg * NC + c] = (ushort_t)f2bf(acc[reg] * isq_s[rg]);
            }
        }
    }
}

// ---- gather2 v2: 10 lanes x uint2 per edge, 6 edges per wave in parallel ----
__global__ void k_gather2(const int* __restrict__ row_ptr, const int* __restrict__ srcs,
                          const uint2* __restrict__ H2b2, const float* __restrict__ isq_d,
                          const float* __restrict__ b2, float* __restrict__ out) {
    __shared__ float4 pt[4][64];     // 4 KB partials
    const int wv = threadIdx.x >> 6;
    const int lane = threadIdx.x & 63;
    const int grp = lane / 10;       // 0..5 active edge slots, 6 = idle lanes 60-63
    const int gl  = lane - grp * 10; // uint2 index within the 80B row
    const int n = blockIdx.x * 4 + wv;

    float a0 = 0.f, a1 = 0.f, a2 = 0.f, a3 = 0.f;
    if (n < NN && grp < 6) {
        int beg = row_ptr[n], end = row_ptr[n + 1];
        int j = beg;
        for (; j + 12 <= end; j += 12) {           // 12 edges in flight
            int eA = j + grp, eB = j + 6 + grp;
            uint2 vA = H2b2[(size_t)srcs[eA] * 10 + gl];
            uint2 vB = H2b2[(size_t)srcs[eB] * 10 + gl];
            a0 += bflo(vA.x) + bflo(vB.x);
            a1 += bfhi(vA.x) + bfhi(vB.x);
            a2 += bflo(vA.y) + bflo(vB.y);
            a3 += bfhi(vA.y) + bfhi(vB.y);
        }
        if (j + 6 <= end) {
            uint2 v = H2b2[(size_t)srcs[j + grp] * 10 + gl];
            a0 += bflo(v.x); a1 += bfhi(v.x);
            a2 += bflo(v.y); a3 += bfhi(v.y);
            j += 6;
        }
        int r = end - j;                            // 0..5 tail edges
        if (grp < r) {
            uint2 v = H2b2[(size_t)srcs[j + grp] * 10 + gl];
            a0 += bflo(v.x); a1 += bfhi(v.x);
            a2 += bflo(v.y); a3 += bfhi(v.y);
        }
    }
    pt[wv][lane] = (float4){a0, a1, a2, a3};
    __syncthreads();

    if (n < NN && lane < 10) {
        float4 s = pt[wv][lane];
#pragma unroll
        for (int g = 1; g < 6; ++g) {
            float4 t = pt[wv][g * 10 + lane];
            s.x += t.x; s.y += t.y; s.z += t.z; s.w += t.w;
        }
        float sc = isq_d[n];
        float4 bv = *(const float4*)&b2[lane * 4];
        float4 o = { s.x * sc + bv.x, s.y * sc + bv.y,
                     s.z * sc + bv.z, s.w * sc + bv.w };
        *(float4*)&out[(size_t)n * NC + lane * 4] = o;
    }
}

extern "C" void kernel_launch(void* const* d_in, const int* in_sizes, int n_in,
                              void* d_out, int out_size, void* d_ws, size_t ws_size,
                              hipStream_t stream) {
    const float* X  = (const float*)d_in[0];
    const int* src  = (const int*)d_in[1];
    const int* dst  = (const int*)d_in[2];
    const float* W1 = (const float*)d_in[3];
    const float* b1 = (const float*)d_in[4];
    const float* W2 = (const float*)d_in[5];
    const float* b2 = (const float*)d_in[6];
    float* out = (float*)d_out;

    // workspace layout in 4-byte words; peak = 10,328,704 words = 39.4 MiB
    int* w = (int*)d_ws;
    uint_t* countsA = (uint_t*)w;              // 784
    uint_t* countsB = countsA + NBUK;          // 784
    uint_t* basesA  = countsB + NBUK;          // 785
    uint_t* basesB  = basesA + NBUK + 1;       // 785
    uint_t* cursA   = basesB + NBUK + 1;       // 784
    uint_t* cursB   = cursA + NBUK;            // 784   (total 4706, pad to 8192)
    float* isq_s    = (float*)(w + 8192);      // NNP
    float* isq_d    = isq_s + NNP;             // NNP
    int* row_ptr    = (int*)(isq_d + NNP);     // NNP (row_ptr[NN] valid)
    ushort_t* W1f   = (ushort_t*)(row_ptr + NNP);              // 32768 bf16 (16384 words)
    ushort_t* W2f   = (ushort_t*)(row_ptr + NNP + 16384);      // 6144 bf16 (3072 words)
    int* Hw         = row_ptr + NNP + 16384 + 3072;            // H region base (word-aligned x4)
    uint_t* edgesA  = (uint_t*)Hw;             // NE words   -- dead before k_gemm1 writes H
    uchar_t* bytesB = (uchar_t*)(Hw + NE);     // NE bytes (400000 words) -- ditto
    ushort_t* H     = (ushort_t*)Hw;           // NN*128 bf16 = 6.4M words (overlaps edgesA/bytesB)
    int* srcs       = Hw + 6400000;            // NE words
    ushort_t* H2b   = (ushort_t*)(srcs + NE);  // NN*40 bf16 = 2M words

    hipMemsetAsync(countsA, 0, 2 * NBUK * sizeof(uint_t), stream);

    // CSR build via two-level bucket sort (no scattered device atomics)
    k_bcount <<<NBLK, 256, 0, stream>>>(src, dst, countsA, countsB, W1, W1f, W2, W2f);
    k_bscan  <<<1, 1024, 0, stream>>>(countsA, countsB, basesA, basesB, cursA, cursB);
    k_bfill  <<<NBLK, 256, 0, stream>>>(src, dst, cursA, cursB, edgesA, bytesB);
    k_bfinish<<<NBUK, 256, 0, stream>>>(basesA, basesB, edgesA, bytesB,
                                        row_ptr, srcs, isq_d, isq_s);

    // layer 1 GEMM (MFMA)  [H overwrites edgesA/bytesB -- both dead now]
    k_gemm1<<<(NN + 63) / 64, 256, 0, stream>>>(X, W1f, isq_s, H);

    // fused: layer-1 aggregate + bias/relu + layer-2 GEMM (MFMA) -> bf16 H2
    k_agg1_gemm2<<<NN / 16, 256, 0, stream>>>(row_ptr, srcs, (const uint4*)H,
                                              isq_d, isq_s, b1, W2f, H2b);

    // layer-2 aggregate + bias -> fp32 out
    k_gather2<<<(NN + 3) / 4, 256, 0, stream>>>(row_ptr, srcs, (const uint2*)H2b,
                                                isq_d, b2, out);
}

// Round 4
// 392.678 us; speedup vs baseline: 1.5834x; 1.0274x over previous
//
#include <hip/hip_runtime.h>
#include <hip/hip_bf16.h>
#include <stdint.h>

#define NN 100000      // nodes
#define NE 1600000     // edges
#define INF 256        // in feats
#define HF 128         // hidden feats
#define NC 40          // classes
#define NNP 100352     // NN padded to multiple of 512
#define NBUK 784       // NNP / 128 coarse buckets
#define BKSH 7         // bucket = node >> 7 (128 nodes per bucket)
#define NBLK 128       // blocks for bcount / bfill
#define CHUNK 12500    // edges per block (128 * 12500 == NE)

typedef unsigned short ushort_t;
typedef unsigned int uint_t;
typedef unsigned char uchar_t;
typedef __attribute__((ext_vector_type(8))) short short8;   // 8 bf16 (4 VGPR)
typedef __attribute__((ext_vector_type(4))) float f32x4;

__device__ __forceinline__ float bflo(uint_t u) {
    union { uint_t i; float f; } v; v.i = u << 16; return v.f;
}
__device__ __forceinline__ float bfhi(uint_t u) {
    union { uint_t i; float f; } v; v.i = u & 0xffff0000u; return v.f;
}
__device__ __forceinline__ uint_t f2bf(float f) {
    __hip_bfloat16 h = __float2bfloat16(f);
    return (uint_t)*reinterpret_cast<ushort_t*>(&h);
}

// ---- bucket counts (LDS hist, coalesced flush) + W1/W2 fragment conversion ----
// W1f layout: (k,n) -> (((ks*8+ct)*4+q)*16+ln)*8 + j  (ks=k/32,q=(k/8)%4,j=k%8,ct=n/16,ln=n&15)
// W2f layout: K=128, N padded 40->48: (((ks*3+ct)*4+q)*16+ln)*8 + j
__launch_bounds__(256)
__global__ void k_bcount(const int* __restrict__ src, const int* __restrict__ dst,
                         uint_t* __restrict__ countsA, uint_t* __restrict__ countsB,
                         const float* __restrict__ W1, ushort_t* __restrict__ W1f,
                         const float* __restrict__ W2, ushort_t* __restrict__ W2f) {
    __shared__ uint_t hA[NBUK], hB[NBUK];
    for (int t = threadIdx.x; t < NBUK; t += 256) { hA[t] = 0; hB[t] = 0; }

    // fused one-time weight conversion (grid is exactly 32768 threads)
    int i = blockIdx.x * 256 + threadIdx.x;
    {
        int k = i >> 7, n = i & 127;
        int ks = k >> 5, q = (k >> 3) & 3, j = k & 7;
        int ct = n >> 4, ln = n & 15;
        W1f[(((ks * 8 + ct) * 4 + q) * 16 + ln) * 8 + j] = (ushort_t)f2bf(W1[i]);
    }
    if (i < HF * 48) {
        int k = i / 48, n = i % 48;
        int ks = k >> 5, q = (k >> 3) & 3, j = k & 7;
        int ct = n >> 4, ln = n & 15;
        float v = (n < NC) ? W2[k * NC + n] : 0.0f;
        W2f[(((ks * 3 + ct) * 4 + q) * 16 + ln) * 8 + j] = (ushort_t)f2bf(v);
    }
    __syncthreads();

    const int beg = blockIdx.x * CHUNK, end = beg + CHUNK;
    for (int e = beg + threadIdx.x; e < end; e += 256) {
        atomicAdd(&hA[(uint_t)dst[e] >> BKSH], 1u);
        atomicAdd(&hB[(uint_t)src[e] >> BKSH], 1u);
    }
    __syncthreads();
    for (int t = threadIdx.x; t < NBUK; t += 256) {
        if (hA[t]) atomicAdd(&countsA[t], hA[t]);
        if (hB[t]) atomicAdd(&countsB[t], hB[t]);
    }
}

// ---- exclusive scan of both bucket-count arrays; init bases + cursors ----
__global__ void k_bscan(const uint_t* __restrict__ countsA, const uint_t* __restrict__ countsB,
                        uint_t* __restrict__ basesA, uint_t* __restrict__ basesB,
                        uint_t* __restrict__ cursA, uint_t* __restrict__ cursB) {
    __shared__ uint_t s[1024];
    const int t = threadIdx.x;
    uint_t v = (t < NBUK) ? countsA[t] : 0;
    s[t] = v; __syncthreads();
    for (int off = 1; off < 1024; off <<= 1) {
        uint_t tv = (t >= off) ? s[t - off] : 0;
        __syncthreads();
        s[t] += tv;
        __syncthreads();
    }
    if (t < NBUK) { uint_t e = s[t] - v; basesA[t] = e; cursA[t] = e; }
    if (t == 0) basesA[NBUK] = NE;
    __syncthreads();
    v = (t < NBUK) ? countsB[t] : 0;
    s[t] = v; __syncthreads();
    for (int off = 1; off < 1024; off <<= 1) {
        uint_t tv = (t >= off) ? s[t - off] : 0;
        __syncthreads();
        s[t] += tv;
        __syncthreads();
    }
    if (t < NBUK) { uint_t e = s[t] - v; basesB[t] = e; cursB[t] = e; }
    if (t == 0) basesB[NBUK] = NE;
}

// ---- bucket scatter: per-block LDS hist, one cursor claim per (block,bucket),
//      then plain cached stores (combine in L2 — no device atomics per edge) ----
__launch_bounds__(256)
__global__ void k_bfill(const int* __restrict__ src, const int* __restrict__ dst,
                        uint_t* __restrict__ cursA, uint_t* __restrict__ cursB,
                        uint_t* __restrict__ edgesA, uchar_t* __restrict__ bytesB) {
    __shared__ uint_t hA[NBUK], hB[NBUK];
    for (int t = threadIdx.x; t < NBUK; t += 256) { hA[t] = 0; hB[t] = 0; }
    __syncthreads();
    const int beg = blockIdx.x * CHUNK, end = beg + CHUNK;
    for (int e = beg + threadIdx.x; e < end; e += 256) {
        atomicAdd(&hA[(uint_t)dst[e] >> BKSH], 1u);
        atomicAdd(&hB[(uint_t)src[e] >> BKSH], 1u);
    }
    __syncthreads();
    for (int t = threadIdx.x; t < NBUK; t += 256) {
        uint_t c = hA[t];
        hA[t] = c ? atomicAdd(&cursA[t], c) : 0;
        c = hB[t];
        hB[t] = c ? atomicAdd(&cursB[t], c) : 0;
    }
    __syncthreads();
    for (int e = beg + threadIdx.x; e < end; e += 256) {
        uint_t d = (uint_t)dst[e], s = (uint_t)src[e];
        uint_t pA = atomicAdd(&hA[d >> BKSH], 1u);     // LDS cursor
        edgesA[pA] = ((d & 127u) << 17) | s;           // 24-bit packed (dstLow, src)
        uint_t pB = atomicAdd(&hB[s >> BKSH], 1u);     // LDS cursor
        bytesB[pB] = (uchar_t)(s & 127u);
    }
}

// ---- per-bucket finish: fine histogram -> row_ptr/isq_d, local counting
//      sort -> srcs; plus src-side byte histogram -> isq_s ----
__launch_bounds__(256)
__global__ void k_bfinish(const uint_t* __restrict__ basesA, const uint_t* __restrict__ basesB,
                          const uint_t* __restrict__ edgesA, const uchar_t* __restrict__ bytesB,
                          int* __restrict__ row_ptr, int* __restrict__ srcs,
                          float* __restrict__ isq_d, float* __restrict__ isq_s) {
    __shared__ uint_t h[128], sc[128], cur[128];
    const int b = blockIdx.x, t = threadIdx.x;
    const uint_t beg = basesA[b], end = basesA[b + 1];
    if (t < 128) h[t] = 0;
    __syncthreads();
    for (uint_t e = beg + t; e < end; e += 256)
        atomicAdd(&h[(edgesA[e] >> 17) & 127u], 1u);
    __syncthreads();
    uint_t v = (t < 128) ? h[t] : 0;
    if (t < 128) sc[t] = v;
    __syncthreads();
    for (int off = 1; off < 128; off <<= 1) {
        uint_t tv = (t >= off && t < 128) ? sc[t - off] : 0;
        __syncthreads();
        if (t < 128) sc[t] += tv;
        __syncthreads();
    }
    if (t < 128) {
        uint_t excl = sc[t] - v;
        row_ptr[b * 128 + t] = (int)(beg + excl);
        isq_d[b * 128 + t] = rsqrtf(fmaxf((float)v, 1.0f));
        cur[t] = excl;
    }
    __syncthreads();
    for (uint_t e = beg + t; e < end; e += 256) {
        uint_t u = edgesA[e];
        uint_t p = atomicAdd(&cur[(u >> 17) & 127u], 1u);
        srcs[beg + p] = (int)(u & 0x1FFFFu);
    }
    __syncthreads();
    if (t < 128) h[t] = 0;
    __syncthreads();
    const uint_t begB = basesB[b], endB = basesB[b + 1];
    for (uint_t e = begB + t; e < endB; e += 256)
        atomicAdd(&h[bytesB[e]], 1u);
    __syncthreads();
    if (t < 128) isq_s[b * 128 + t] = rsqrtf(fmaxf((float)h[t], 1.0f));
}

// ---- GEMM1 (MFMA): H[N,128](bf16) = (X[N,256] @ W1) * isq_s[row] ----
__launch_bounds__(256)
__global__ void k_gemm1(const float* __restrict__ X, const ushort_t* __restrict__ W1f,
                        const float* __restrict__ isq_s, ushort_t* __restrict__ H) {
    const int wv = threadIdx.x >> 6;
    const int lane = threadIdx.x & 63;
    const int ln = lane & 15;
    const int q  = lane >> 4;
    const int r0 = blockIdx.x * 64 + wv * 16;
    const int rm = min(r0 + ln, NN - 1);     // A row for this lane (m = ln)

    f32x4 acc[8];
#pragma unroll
    for (int ct = 0; ct < 8; ++ct) acc[ct] = (f32x4){0.f, 0.f, 0.f, 0.f};

    const float* xp = &X[(size_t)rm * INF + q * 8];
    const uint4* wf = (const uint4*)W1f;

    for (int ks = 0; ks < 8; ++ks) {
        float4 xa = *(const float4*)xp;
        float4 xb = *(const float4*)(xp + 4);
        xp += 32;
        short8 af;
        af[0] = (short)f2bf(xa.x); af[1] = (short)f2bf(xa.y);
        af[2] = (short)f2bf(xa.z); af[3] = (short)f2bf(xa.w);
        af[4] = (short)f2bf(xb.x); af[5] = (short)f2bf(xb.y);
        af[6] = (short)f2bf(xb.z); af[7] = (short)f2bf(xb.w);
#pragma unroll
        for (int ct = 0; ct < 8; ++ct) {
            union { uint4 u; short8 s; } bv;
            bv.u = wf[(size_t)(ks * 8 + ct) * 64 + lane];
            acc[ct] = __builtin_amdgcn_mfma_f32_16x16x32_bf16(af, bv.s, acc[ct], 0, 0, 0);
        }
    }

#pragma unroll
    for (int reg = 0; reg < 4; ++reg) {
        int r = r0 + q * 4 + reg;
        if (r < NN) {
            float s = isq_s[r];
#pragma unroll
            for (int ct = 0; ct < 8; ++ct)
                H[(size_t)r * HF + ct * 16 + ln] = (ushort_t)f2bf(acc[ct][reg] * s);
        }
    }
}

// unpack-accumulate one 16B slice (8 bf16 feats) into a[0..7]
#define ACC8(v) { a[0] += bflo((v).x); a[1] += bfhi((v).x); \
                  a[2] += bflo((v).y); a[3] += bfhi((v).y); \
                  a[4] += bflo((v).z); a[5] += bfhi((v).z); \
                  a[6] += bflo((v).w); a[7] += bfhi((v).w); }

// ---- fused layer1-aggregate + layer2 GEMM (MFMA form) ----
__launch_bounds__(256)
__global__ void k_agg1_gemm2(const int* __restrict__ row_ptr, const int* __restrict__ srcs,
                             const uint4* __restrict__ H16, const float* __restrict__ isq_d,
                             const float* __restrict__ isq_s, const float* __restrict__ b1,
                             const ushort_t* __restrict__ W2f, ushort_t* __restrict__ H2b) {
    __shared__ uint4 h1s[16][16];   // 4 KB: [local node][swizzled k-slice]
    const int wv = threadIdx.x >> 6;
    const int lane = threadIdx.x & 63;
    const int grp = lane >> 4;   // edge slot 0..3
    const int gl  = lane & 15;   // uint4 index within 256B row
    const int n0 = blockIdx.x * 16;   // 6250 blocks * 16 == NN exactly

    const float4 bva = ((const float4*)b1)[gl * 2];
    const float4 bvb = ((const float4*)b1)[gl * 2 + 1];

    for (int ni = 0; ni < 4; ++ni) {
        const int rl = wv * 4 + ni;        // local node 0..15
        const int n = n0 + rl;
        float a[8];
#pragma unroll
        for (int k = 0; k < 8; ++k) a[k] = 0.0f;

        int beg = row_ptr[n], end = row_ptr[n + 1];
        int j = beg;
        for (; j + 16 <= end; j += 16) {   // 16 edges/iter, 4 KB in flight
            int sA = srcs[j + grp];
            int sB = srcs[j + 4 + grp];
            int sC = srcs[j + 8 + grp];
            int sD = srcs[j + 12 + grp];
            uint4 vA = H16[(size_t)sA * 16 + gl];
            uint4 vB = H16[(size_t)sB * 16 + gl];
            uint4 vC = H16[(size_t)sC * 16 + gl];
            uint4 vD = H16[(size_t)sD * 16 + gl];
            ACC8(vA); ACC8(vB); ACC8(vC); ACC8(vD);
        }
        for (; j + 8 <= end; j += 8) {
            int sA = srcs[j + grp];
            int sB = srcs[j + 4 + grp];
            uint4 vA = H16[(size_t)sA * 16 + gl];
            uint4 vB = H16[(size_t)sB * 16 + gl];
            ACC8(vA); ACC8(vB);
        }
        for (; j + 4 <= end; j += 4) {
            uint4 v = H16[(size_t)srcs[j + grp] * 16 + gl];
            ACC8(v);
        }
        int r = end - j;                   // 0..3 tail edges
        if (grp < r) {
            uint4 v = H16[(size_t)srcs[j + grp] * 16 + gl];
            ACC8(v);
        }
        // combine the 4 edge-slot partials (lane bits 4 and 5)
#pragma unroll
        for (int k = 0; k < 8; ++k) {
            a[k] += __shfl_xor(a[k], 16);
            a[k] += __shfl_xor(a[k], 32);
        }
        if (lane < 16) {
            float sc = isq_d[n];
            uint_t p0 = f2bf(fmaxf(a[0] * sc + bva.x, 0.0f))
                      | (f2bf(fmaxf(a[1] * sc + bva.y, 0.0f)) << 16);
            uint_t p1 = f2bf(fmaxf(a[2] * sc + bva.z, 0.0f))
                      | (f2bf(fmaxf(a[3] * sc + bva.w, 0.0f)) << 16);
            uint_t p2 = f2bf(fmaxf(a[4] * sc + bvb.x, 0.0f))
                      | (f2bf(fmaxf(a[5] * sc + bvb.y, 0.0f)) << 16);
            uint_t p3 = f2bf(fmaxf(a[6] * sc + bvb.z, 0.0f))
                      | (f2bf(fmaxf(a[7] * sc + bvb.w, 0.0f)) << 16);
            h1s[rl][gl ^ rl] = (uint4){p0, p1, p2, p3};   // XOR-swizzle vs row
        }
    }
    __syncthreads();

    // GEMM2: waves 0-2 each own one 16-col tile (N padded 40->48)
    if (wv < 3) {
        const int q = grp;     // lane>>4
        const int ln = gl;     // lane&15; A row (= local node) for this lane
        f32x4 acc = (f32x4){0.f, 0.f, 0.f, 0.f};
        const uint4* wf = (const uint4*)W2f;
#pragma unroll
        for (int ks = 0; ks < 4; ++ks) {
            union { uint4 u; short8 s; } av, bv;
            av.u = h1s[ln][(ks * 4 + q) ^ ln];            // matching swizzle
            bv.u = wf[(size_t)(ks * 3 + wv) * 64 + lane];
            acc = __builtin_amdgcn_mfma_f32_16x16x32_bf16(av.s, bv.s, acc, 0, 0, 0);
        }
        int c = wv * 16 + ln;
        if (c < NC) {
#pragma unroll
            for (int reg = 0; reg < 4; ++reg) {
                int rg = n0 + q * 4 + reg;
                H2b[(size_t)rg * NC + c] = (ushort_t)f2bf(acc[reg] * isq_s[rg]);
            }
        }
    }
}

// ---- gather2 v3: 5 lanes x uint4 per edge (80B row), 12 edge slots,
//      24 edges (1.9KB) in flight per wave in the main tier ----
__launch_bounds__(256)
__global__ void k_gather2(const int* __restrict__ row_ptr, const int* __restrict__ srcs,
                          const uint4* __restrict__ H2b4, const float* __restrict__ isq_d,
                          const float* __restrict__ b2, float* __restrict__ out) {
    __shared__ float pt[4][64][9];   // 9.2 KB, stride-9 pad (2-way aliasing only)
    const int wv = threadIdx.x >> 6;
    const int lane = threadIdx.x & 63;
    const int grp = lane / 5;        // 0..11 active edge slots; 12 = idle lanes 60-63
    const int gl  = lane - grp * 5;  // uint4 index within the 80B row
    const int n = blockIdx.x * 4 + wv;

    float a[8];
#pragma unroll
    for (int k = 0; k < 8; ++k) a[k] = 0.0f;

    if (n < NN && grp < 12) {
        int beg = row_ptr[n], end = row_ptr[n + 1];
        int j = beg;
        for (; j + 24 <= end; j += 24) {            // 24 edges, 2 loads in flight
            int sA = srcs[j + grp];
            int sB = srcs[j + 12 + grp];
            uint4 vA = H2b4[(size_t)sA * 5 + gl];
            uint4 vB = H2b4[(size_t)sB * 5 + gl];
            ACC8(vA); ACC8(vB);
        }
        if (j + 12 <= end) {                         // 12-edge tier
            uint4 v = H2b4[(size_t)srcs[j + grp] * 5 + gl];
            ACC8(v);
            j += 12;
        }
        int r = end - j;                             // 0..11 tail edges
        if (grp < r) {
            uint4 v = H2b4[(size_t)srcs[j + grp] * 5 + gl];
            ACC8(v);
        }
    }
#pragma unroll
    for (int k = 0; k < 8; ++k) pt[wv][lane][k] = a[k];
    __syncthreads();

    if (n < NN && lane < NC) {
        const int g2 = lane >> 3;    // which uint4 slice (0..4)
        const int i2 = lane & 7;     // feat within slice
        float s = 0.0f;
#pragma unroll
        for (int g = 0; g < 12; ++g)
            s += pt[wv][g * 5 + g2][i2];
        out[(size_t)n * NC + lane] = s * isq_d[n] + b2[lane];
    }
}

extern "C" void kernel_launch(void* const* d_in, const int* in_sizes, int n_in,
                              void* d_out, int out_size, void* d_ws, size_t ws_size,
                              hipStream_t stream) {
    const float* X  = (const float*)d_in[0];
    const int* src  = (const int*)d_in[1];
    const int* dst  = (const int*)d_in[2];
    const float* W1 = (const float*)d_in[3];
    const float* b1 = (const float*)d_in[4];
    const float* W2 = (const float*)d_in[5];
    const float* b2 = (const float*)d_in[6];
    float* out = (float*)d_out;

    // workspace layout in 4-byte words; peak = 10,328,704 words = 39.4 MiB
    int* w = (int*)d_ws;
    uint_t* countsA = (uint_t*)w;              // 784
    uint_t* countsB = countsA + NBUK;          // 784
    uint_t* basesA  = countsB + NBUK;          // 785
    uint_t* basesB  = basesA + NBUK + 1;       // 785
    uint_t* cursA   = basesB + NBUK + 1;       // 784
    uint_t* cursB   = cursA + NBUK;            // 784   (total 4706, pad to 8192)
    float* isq_s    = (float*)(w + 8192);      // NNP
    float* isq_d    = isq_s + NNP;             // NNP
    int* row_ptr    = (int*)(isq_d + NNP);     // NNP (row_ptr[NN] valid)
    ushort_t* W1f   = (ushort_t*)(row_ptr + NNP);              // 32768 bf16 (16384 words)
    ushort_t* W2f   = (ushort_t*)(row_ptr + NNP + 16384);      // 6144 bf16 (3072 words)
    int* Hw         = row_ptr + NNP + 16384 + 3072;            // H region base (16B aligned)
    uint_t* edgesA  = (uint_t*)Hw;             // NE words   -- dead before k_gemm1 writes H
    uchar_t* bytesB = (uchar_t*)(Hw + NE);     // NE bytes (400000 words) -- ditto
    ushort_t* H     = (ushort_t*)Hw;           // NN*128 bf16 = 6.4M words (overlaps edgesA/bytesB)
    int* srcs       = Hw + 6400000;            // NE words
    ushort_t* H2b   = (ushort_t*)(srcs + NE);  // NN*40 bf16 = 2M words (16B aligned)

    hipMemsetAsync(countsA, 0, 2 * NBUK * sizeof(uint_t), stream);

    // CSR build via two-level bucket sort (no scattered device atomics)
    k_bcount <<<NBLK, 256, 0, stream>>>(src, dst, countsA, countsB, W1, W1f, W2, W2f);
    k_bscan  <<<1, 1024, 0, stream>>>(countsA, countsB, basesA, basesB, cursA, cursB);
    k_bfill  <<<NBLK, 256, 0, stream>>>(src, dst, cursA, cursB, edgesA, bytesB);
    k_bfinish<<<NBUK, 256, 0, stream>>>(basesA, basesB, edgesA, bytesB,
                                        row_ptr, srcs, isq_d, isq_s);

    // layer 1 GEMM (MFMA)  [H overwrites edgesA/bytesB -- both dead now]
    k_gemm1<<<(NN + 63) / 64, 256, 0, stream>>>(X, W1f, isq_s, H);

    // fused: layer-1 aggregate + bias/relu + layer-2 GEMM (MFMA) -> bf16 H2
    k_agg1_gemm2<<<NN / 16, 256, 0, stream>>>(row_ptr, srcs, (const uint4*)H,
                                              isq_d, isq_s, b1, W2f, H2b);

    // layer-2 aggregate + bias -> fp32 out
    k_gather2<<<(NN + 3) / 4, 256, 0, stream>>>(row_ptr, srcs, (const uint4*)H2b,
                                                isq_d, b2, out);
}

// Round 5
// 371.145 us; speedup vs baseline: 1.6752x; 1.0580x over previous
//
#include <hip/hip_runtime.h>
#include <hip/hip_bf16.h>
#include <stdint.h>

#define NN 100000      // nodes
#define NE 1600000     // edges
#define INF 256        // in feats
#define HF 128         // hidden feats
#define NC 40          // classes
#define NNP 100352     // NN padded to multiple of 512
#define NBUK 784       // NNP / 128 coarse buckets
#define BKSH 7         // bucket = node >> 7 (128 nodes per bucket)
#define NBLK 256       // blocks for bcount / bfill (all CUs)
#define CHUNK 6250     // edges per block (256 * 6250 == NE)

typedef unsigned short ushort_t;
typedef unsigned int uint_t;
typedef unsigned char uchar_t;
typedef __attribute__((ext_vector_type(8))) short short8;   // 8 bf16 (4 VGPR)
typedef __attribute__((ext_vector_type(4))) float f32x4;

__device__ __forceinline__ float bflo(uint_t u) {
    union { uint_t i; float f; } v; v.i = u << 16; return v.f;
}
__device__ __forceinline__ float bfhi(uint_t u) {
    union { uint_t i; float f; } v; v.i = u & 0xffff0000u; return v.f;
}
__device__ __forceinline__ uint_t f2bf(float f) {
    __hip_bfloat16 h = __float2bfloat16(f);
    return (uint_t)*reinterpret_cast<ushort_t*>(&h);
}

// ---- bucket counts (LDS hist, coalesced flush) + W1/W2 fragment conversion ----
// W1f layout: (k,n) -> (((ks*8+ct)*4+q)*16+ln)*8 + j  (ks=k/32,q=(k/8)%4,j=k%8,ct=n/16,ln=n&15)
// W2f layout: K=128, N padded 40->48: (((ks*3+ct)*4+q)*16+ln)*8 + j
__launch_bounds__(256)
__global__ void k_bcount(const int* __restrict__ src, const int* __restrict__ dst,
                         uint_t* __restrict__ countsA, uint_t* __restrict__ countsB,
                         const float* __restrict__ W1, ushort_t* __restrict__ W1f,
                         const float* __restrict__ W2, ushort_t* __restrict__ W2f) {
    __shared__ uint_t hA[NBUK], hB[NBUK];
    for (int t = threadIdx.x; t < NBUK; t += 256) { hA[t] = 0; hB[t] = 0; }

    // fused one-time weight conversion
    int i = blockIdx.x * 256 + threadIdx.x;
    if (i < INF * HF) {
        int k = i >> 7, n = i & 127;
        int ks = k >> 5, q = (k >> 3) & 3, j = k & 7;
        int ct = n >> 4, ln = n & 15;
        W1f[(((ks * 8 + ct) * 4 + q) * 16 + ln) * 8 + j] = (ushort_t)f2bf(W1[i]);
    }
    if (i < HF * 48) {
        int k = i / 48, n = i % 48;
        int ks = k >> 5, q = (k >> 3) & 3, j = k & 7;
        int ct = n >> 4, ln = n & 15;
        float v = (n < NC) ? W2[k * NC + n] : 0.0f;
        W2f[(((ks * 3 + ct) * 4 + q) * 16 + ln) * 8 + j] = (ushort_t)f2bf(v);
    }
    __syncthreads();

    const int beg = blockIdx.x * CHUNK, end = beg + CHUNK;
    for (int e = beg + threadIdx.x; e < end; e += 256) {
        atomicAdd(&hA[(uint_t)dst[e] >> BKSH], 1u);
        atomicAdd(&hB[(uint_t)src[e] >> BKSH], 1u);
    }
    __syncthreads();
    for (int t = threadIdx.x; t < NBUK; t += 256) {
        if (hA[t]) atomicAdd(&countsA[t], hA[t]);
        if (hB[t]) atomicAdd(&countsB[t], hB[t]);
    }
}

// ---- exclusive scan of both bucket-count arrays; init bases + cursors ----
__global__ void k_bscan(const uint_t* __restrict__ countsA, const uint_t* __restrict__ countsB,
                        uint_t* __restrict__ basesA, uint_t* __restrict__ basesB,
                        uint_t* __restrict__ cursA, uint_t* __restrict__ cursB) {
    __shared__ uint_t s[1024];
    const int t = threadIdx.x;
    uint_t v = (t < NBUK) ? countsA[t] : 0;
    s[t] = v; __syncthreads();
    for (int off = 1; off < 1024; off <<= 1) {
        uint_t tv = (t >= off) ? s[t - off] : 0;
        __syncthreads();
        s[t] += tv;
        __syncthreads();
    }
    if (t < NBUK) { uint_t e = s[t] - v; basesA[t] = e; cursA[t] = e; }
    if (t == 0) basesA[NBUK] = NE;
    __syncthreads();
    v = (t < NBUK) ? countsB[t] : 0;
    s[t] = v; __syncthreads();
    for (int off = 1; off < 1024; off <<= 1) {
        uint_t tv = (t >= off) ? s[t - off] : 0;
        __syncthreads();
        s[t] += tv;
        __syncthreads();
    }
    if (t < NBUK) { uint_t e = s[t] - v; basesB[t] = e; cursB[t] = e; }
    if (t == 0) basesB[NBUK] = NE;
}

// ---- bucket scatter: per-block LDS hist, one cursor claim per (block,bucket),
//      then plain cached stores (combine in L2 — no device atomics per edge) ----
__launch_bounds__(256)
__global__ void k_bfill(const int* __restrict__ src, const int* __restrict__ dst,
                        uint_t* __restrict__ cursA, uint_t* __restrict__ cursB,
                        uint_t* __restrict__ edgesA, uchar_t* __restrict__ bytesB) {
    __shared__ uint_t hA[NBUK], hB[NBUK];
    for (int t = threadIdx.x; t < NBUK; t += 256) { hA[t] = 0; hB[t] = 0; }
    __syncthreads();
    const int beg = blockIdx.x * CHUNK, end = beg + CHUNK;
    for (int e = beg + threadIdx.x; e < end; e += 256) {
        atomicAdd(&hA[(uint_t)dst[e] >> BKSH], 1u);
        atomicAdd(&hB[(uint_t)src[e] >> BKSH], 1u);
    }
    __syncthreads();
    for (int t = threadIdx.x; t < NBUK; t += 256) {
        uint_t c = hA[t];
        hA[t] = c ? atomicAdd(&cursA[t], c) : 0;
        c = hB[t];
        hB[t] = c ? atomicAdd(&cursB[t], c) : 0;
    }
    __syncthreads();
    for (int e = beg + threadIdx.x; e < end; e += 256) {
        uint_t d = (uint_t)dst[e], s = (uint_t)src[e];
        uint_t pA = atomicAdd(&hA[d >> BKSH], 1u);     // LDS cursor
        edgesA[pA] = ((d & 127u) << 17) | s;           // 24-bit packed (dstLow, src)
        uint_t pB = atomicAdd(&hB[s >> BKSH], 1u);     // LDS cursor
        bytesB[pB] = (uchar_t)(s & 127u);
    }
}

// ---- per-bucket finish: fine histogram -> row_ptr/isq_d, local counting
//      sort -> srcs; plus src-side byte histogram -> isq_s ----
__launch_bounds__(256)
__global__ void k_bfinish(const uint_t* __restrict__ basesA, const uint_t* __restrict__ basesB,
                          const uint_t* __restrict__ edgesA, const uchar_t* __restrict__ bytesB,
                          int* __restrict__ row_ptr, int* __restrict__ srcs,
                          float* __restrict__ isq_d, float* __restrict__ isq_s) {
    __shared__ uint_t h[128], sc[128], cur[128];
    const int b = blockIdx.x, t = threadIdx.x;
    const uint_t beg = basesA[b], end = basesA[b + 1];
    if (t < 128) h[t] = 0;
    __syncthreads();
    for (uint_t e = beg + t; e < end; e += 256)
        atomicAdd(&h[(edgesA[e] >> 17) & 127u], 1u);
    __syncthreads();
    uint_t v = (t < 128) ? h[t] : 0;
    if (t < 128) sc[t] = v;
    __syncthreads();
    for (int off = 1; off < 128; off <<= 1) {
        uint_t tv = (t >= off && t < 128) ? sc[t - off] : 0;
        __syncthreads();
        if (t < 128) sc[t] += tv;
        __syncthreads();
    }
    if (t < 128) {
        uint_t excl = sc[t] - v;
        row_ptr[b * 128 + t] = (int)(beg + excl);
        isq_d[b * 128 + t] = rsqrtf(fmaxf((float)v, 1.0f));
        cur[t] = excl;
    }
    __syncthreads();
    for (uint_t e = beg + t; e < end; e += 256) {
        uint_t u = edgesA[e];
        uint_t p = atomicAdd(&cur[(u >> 17) & 127u], 1u);
        srcs[beg + p] = (int)(u & 0x1FFFFu);
    }
    __syncthreads();
    if (t < 128) h[t] = 0;
    __syncthreads();
    const uint_t begB = basesB[b], endB = basesB[b + 1];
    for (uint_t e = begB + t; e < endB; e += 256)
        atomicAdd(&h[bytesB[e]], 1u);
    __syncthreads();
    if (t < 128) isq_s[b * 128 + t] = rsqrtf(fmaxf((float)h[t], 1.0f));
}

// ---- GEMM1 (MFMA): H[N,128](bf16) = (X[N,256] @ W1) * isq_s[row] ----
// Hoisted-load form: each lane issues all 16 independent float4 loads for its
// 256B X row-slice up front (latency paid ~once, not 8x), converts to 8 bf16
// fragments, then streams 64 MFMAs against L2-hot W1f.
__launch_bounds__(256, 4)
__global__ void k_gemm1(const float* __restrict__ X, const ushort_t* __restrict__ W1f,
                        const float* __restrict__ isq_s, ushort_t* __restrict__ H) {
    const int wv = threadIdx.x >> 6;
    const int lane = threadIdx.x & 63;
    const int ln = lane & 15;
    const int q  = lane >> 4;
    const int r0 = blockIdx.x * 64 + wv * 16;
    const int rm = min(r0 + ln, NN - 1);     // A row for this lane (m = ln)

    f32x4 acc[8];
#pragma unroll
    for (int ct = 0; ct < 8; ++ct) acc[ct] = (f32x4){0.f, 0.f, 0.f, 0.f};

    const float* xp = &X[(size_t)rm * INF + q * 8];
    const uint4* wf = (const uint4*)W1f;

    float4 xv[16];
#pragma unroll
    for (int t = 0; t < 8; ++t) {
        xv[2 * t]     = *(const float4*)(xp + t * 32);
        xv[2 * t + 1] = *(const float4*)(xp + t * 32 + 4);
    }
    short8 af[8];
#pragma unroll
    for (int t = 0; t < 8; ++t) {
        af[t][0] = (short)f2bf(xv[2 * t].x);
        af[t][1] = (short)f2bf(xv[2 * t].y);
        af[t][2] = (short)f2bf(xv[2 * t].z);
        af[t][3] = (short)f2bf(xv[2 * t].w);
        af[t][4] = (short)f2bf(xv[2 * t + 1].x);
        af[t][5] = (short)f2bf(xv[2 * t + 1].y);
        af[t][6] = (short)f2bf(xv[2 * t + 1].z);
        af[t][7] = (short)f2bf(xv[2 * t + 1].w);
    }

#pragma unroll
    for (int ks = 0; ks < 8; ++ks) {
#pragma unroll
        for (int ct = 0; ct < 8; ++ct) {
            union { uint4 u; short8 s; } bv;
            bv.u = wf[(size_t)(ks * 8 + ct) * 64 + lane];
            acc[ct] = __builtin_amdgcn_mfma_f32_16x16x32_bf16(af[ks], bv.s, acc[ct], 0, 0, 0);
        }
    }

#pragma unroll
    for (int reg = 0; reg < 4; ++reg) {
        int r = r0 + q * 4 + reg;
        if (r < NN) {
            float s = isq_s[r];
#pragma unroll
            for (int ct = 0; ct < 8; ++ct)
                H[(size_t)r * HF + ct * 16 + ln] = (ushort_t)f2bf(acc[ct][reg] * s);
        }
    }
}

// unpack-accumulate one 16B slice (8 bf16 feats) into a[0..7]
#define ACC8(v) { a[0] += bflo((v).x); a[1] += bfhi((v).x); \
                  a[2] += bflo((v).y); a[3] += bfhi((v).y); \
                  a[4] += bflo((v).z); a[5] += bfhi((v).z); \
                  a[6] += bflo((v).w); a[7] += bfhi((v).w); }

// ---- fused layer1-aggregate + layer2 GEMM (MFMA form) ----
__launch_bounds__(256)
__global__ void k_agg1_gemm2(const int* __restrict__ row_ptr, const int* __restrict__ srcs,
                             const uint4* __restrict__ H16, const float* __restrict__ isq_d,
                             const float* __restrict__ isq_s, const float* __restrict__ b1,
                             const ushort_t* __restrict__ W2f, ushort_t* __restrict__ H2b) {
    __shared__ uint4 h1s[16][16];   // 4 KB: [local node][swizzled k-slice]
    const int wv = threadIdx.x >> 6;
    const int lane = threadIdx.x & 63;
    const int grp = lane >> 4;   // edge slot 0..3
    const int gl  = lane & 15;   // uint4 index within 256B row
    const int n0 = blockIdx.x * 16;   // 6250 blocks * 16 == NN exactly

    const float4 bva = ((const float4*)b1)[gl * 2];
    const float4 bvb = ((const float4*)b1)[gl * 2 + 1];

    for (int ni = 0; ni < 4; ++ni) {
        const int rl = wv * 4 + ni;        // local node 0..15
        const int n = n0 + rl;
        float a[8];
#pragma unroll
        for (int k = 0; k < 8; ++k) a[k] = 0.0f;

        int beg = row_ptr[n], end = row_ptr[n + 1];
        int j = beg;
        for (; j + 16 <= end; j += 16) {   // 16 edges/iter, 4 KB in flight
            int sA = srcs[j + grp];
            int sB = srcs[j + 4 + grp];
            int sC = srcs[j + 8 + grp];
            int sD = srcs[j + 12 + grp];
            uint4 vA = H16[(size_t)sA * 16 + gl];
            uint4 vB = H16[(size_t)sB * 16 + gl];
            uint4 vC = H16[(size_t)sC * 16 + gl];
            uint4 vD = H16[(size_t)sD * 16 + gl];
            ACC8(vA); ACC8(vB); ACC8(vC); ACC8(vD);
        }
        for (; j + 8 <= end; j += 8) {
            int sA = srcs[j + grp];
            int sB = srcs[j + 4 + grp];
            uint4 vA = H16[(size_t)sA * 16 + gl];
            uint4 vB = H16[(size_t)sB * 16 + gl];
            ACC8(vA); ACC8(vB);
        }
        for (; j + 4 <= end; j += 4) {
            uint4 v = H16[(size_t)srcs[j + grp] * 16 + gl];
            ACC8(v);
        }
        int r = end - j;                   // 0..3 tail edges
        if (grp < r) {
            uint4 v = H16[(size_t)srcs[j + grp] * 16 + gl];
            ACC8(v);
        }
        // combine the 4 edge-slot partials (lane bits 4 and 5)
#pragma unroll
        for (int k = 0; k < 8; ++k) {
            a[k] += __shfl_xor(a[k], 16);
            a[k] += __shfl_xor(a[k], 32);
        }
        if (lane < 16) {
            float sc = isq_d[n];
            uint_t p0 = f2bf(fmaxf(a[0] * sc + bva.x, 0.0f))
                      | (f2bf(fmaxf(a[1] * sc + bva.y, 0.0f)) << 16);
            uint_t p1 = f2bf(fmaxf(a[2] * sc + bva.z, 0.0f))
                      | (f2bf(fmaxf(a[3] * sc + bva.w, 0.0f)) << 16);
            uint_t p2 = f2bf(fmaxf(a[4] * sc + bvb.x, 0.0f))
                      | (f2bf(fmaxf(a[5] * sc + bvb.y, 0.0f)) << 16);
            uint_t p3 = f2bf(fmaxf(a[6] * sc + bvb.z, 0.0f))
                      | (f2bf(fmaxf(a[7] * sc + bvb.w, 0.0f)) << 16);
            h1s[rl][gl ^ rl] = (uint4){p0, p1, p2, p3};   // XOR-swizzle vs row
        }
    }
    __syncthreads();

    // GEMM2: waves 0-2 each own one 16-col tile (N padded 40->48)
    if (wv < 3) {
        const int q = grp;     // lane>>4
        const int ln = gl;     // lane&15; A row (= local node) for this lane
        f32x4 acc = (f32x4){0.f, 0.f, 0.f, 0.f};
        const uint4* wf = (const uint4*)W2f;
#pragma unroll
        for (int ks = 0; ks < 4; ++ks) {
            union { uint4 u; short8 s; } av, bv;
            av.u = h1s[ln][(ks * 4 + q) ^ ln];            // matching swizzle
            bv.u = wf[(size_t)(ks * 3 + wv) * 64 + lane];
            acc = __builtin_amdgcn_mfma_f32_16x16x32_bf16(av.s, bv.s, acc, 0, 0, 0);
        }
        int c = wv * 16 + ln;
        if (c < NC) {
#pragma unroll
            for (int reg = 0; reg < 4; ++reg) {
                int rg = n0 + q * 4 + reg;
                H2b[(size_t)rg * NC + c] = (ushort_t)f2bf(acc[reg] * isq_s[rg]);
            }
        }
    }
}

// ---- gather2 v3: 5 lanes x uint4 per edge (80B row), 12 edge slots,
//      24 edges (1.9KB) in flight per wave in the main tier ----
__launch_bounds__(256)
__global__ void k_gather2(const int* __restrict__ row_ptr, const int* __restrict__ srcs,
                          const uint4* __restrict__ H2b4, const float* __restrict__ isq_d,
                          const float* __restrict__ b2, float* __restrict__ out) {
    __shared__ float pt[4][64][9];   // 9.2 KB, stride-9 pad (2-way aliasing only)
    const int wv = threadIdx.x >> 6;
    const int lane = threadIdx.x & 63;
    const int grp = lane / 5;        // 0..11 active edge slots; 12 = idle lanes 60-63
    const int gl  = lane - grp * 5;  // uint4 index within the 80B row
    const int n = blockIdx.x * 4 + wv;

    float a[8];
#pragma unroll
    for (int k = 0; k < 8; ++k) a[k] = 0.0f;

    if (n < NN && grp < 12) {
        int beg = row_ptr[n], end = row_ptr[n + 1];
        int j = beg;
        for (; j + 24 <= end; j += 24) {            // 24 edges, 2 loads in flight
            int sA = srcs[j + grp];
            int sB = srcs[j + 12 + grp];
            uint4 vA = H2b4[(size_t)sA * 5 + gl];
            uint4 vB = H2b4[(size_t)sB * 5 + gl];
            ACC8(vA); ACC8(vB);
        }
        if (j + 12 <= end) {                         // 12-edge tier
            uint4 v = H2b4[(size_t)srcs[j + grp] * 5 + gl];
            ACC8(v);
            j += 12;
        }
        int r = end - j;                             // 0..11 tail edges
        if (grp < r) {
            uint4 v = H2b4[(size_t)srcs[j + grp] * 5 + gl];
            ACC8(v);
        }
    }
#pragma unroll
    for (int k = 0; k < 8; ++k) pt[wv][lane][k] = a[k];
    __syncthreads();

    if (n < NN && lane < NC) {
        const int g2 = lane >> 3;    // which uint4 slice (0..4)
        const int i2 = lane & 7;     // feat within slice
        float s = 0.0f;
#pragma unroll
        for (int g = 0; g < 12; ++g)
            s += pt[wv][g * 5 + g2][i2];
        out[(size_t)n * NC + lane] = s * isq_d[n] + b2[lane];
    }
}

extern "C" void kernel_launch(void* const* d_in, const int* in_sizes, int n_in,
                              void* d_out, int out_size, void* d_ws, size_t ws_size,
                              hipStream_t stream) {
    const float* X  = (const float*)d_in[0];
    const int* src  = (const int*)d_in[1];
    const int* dst  = (const int*)d_in[2];
    const float* W1 = (const float*)d_in[3];
    const float* b1 = (const float*)d_in[4];
    const float* W2 = (const float*)d_in[5];
    const float* b2 = (const float*)d_in[6];
    float* out = (float*)d_out;

    // workspace layout in 4-byte words; peak = 10,328,704 words = 39.4 MiB
    int* w = (int*)d_ws;
    uint_t* countsA = (uint_t*)w;              // 784
    uint_t* countsB = countsA + NBUK;          // 784
    uint_t* basesA  = countsB + NBUK;          // 785
    uint_t* basesB  = basesA + NBUK + 1;       // 785
    uint_t* cursA   = basesB + NBUK + 1;       // 784
    uint_t* cursB   = cursA + NBUK;            // 784   (total 4706, pad to 8192)
    float* isq_s    = (float*)(w + 8192);      // NNP
    float* isq_d    = isq_s + NNP;             // NNP
    int* row_ptr    = (int*)(isq_d + NNP);     // NNP (row_ptr[NN] valid)
    ushort_t* W1f   = (ushort_t*)(row_ptr + NNP);              // 32768 bf16 (16384 words)
    ushort_t* W2f   = (ushort_t*)(row_ptr + NNP + 16384);      // 6144 bf16 (3072 words)
    int* Hw         = row_ptr + NNP + 16384 + 3072;            // H region base (16B aligned)
    uint_t* edgesA  = (uint_t*)Hw;             // NE words   -- dead before k_gemm1 writes H
    uchar_t* bytesB = (uchar_t*)(Hw + NE);     // NE bytes (400000 words) -- ditto
    ushort_t* H     = (ushort_t*)Hw;           // NN*128 bf16 = 6.4M words (overlaps edgesA/bytesB)
    int* srcs       = Hw + 6400000;            // NE words
    ushort_t* H2b   = (ushort_t*)(srcs + NE);  // NN*40 bf16 = 2M words (16B aligned)

    hipMemsetAsync(countsA, 0, 2 * NBUK * sizeof(uint_t), stream);

    // CSR build via two-level bucket sort (no scattered device atomics)
    k_bcount <<<NBLK, 256, 0, stream>>>(src, dst, countsA, countsB, W1, W1f, W2, W2f);
    k_bscan  <<<1, 1024, 0, stream>>>(countsA, countsB, basesA, basesB, cursA, cursB);
    k_bfill  <<<NBLK, 256, 0, stream>>>(src, dst, cursA, cursB, edgesA, bytesB);
    k_bfinish<<<NBUK, 256, 0, stream>>>(basesA, basesB, edgesA, bytesB,
                                        row_ptr, srcs, isq_d, isq_s);

    // layer 1 GEMM (MFMA)  [H overwrites edgesA/bytesB -- both dead now]
    k_gemm1<<<(NN + 63) / 64, 256, 0, stream>>>(X, W1f, isq_s, H);

    // fused: layer-1 aggregate + bias/relu + layer-2 GEMM (MFMA) -> bf16 H2
    k_agg1_gemm2<<<NN / 16, 256, 0, stream>>>(row_ptr, srcs, (const uint4*)H,
                                              isq_d, isq_s, b1, W2f, H2b);

    // layer-2 aggregate + bias -> fp32 out
    k_gather2<<<(NN + 3) / 4, 256, 0, stream>>>(row_ptr, srcs, (const uint4*)H2b,
                                                isq_d, b2, out);
}